// Round 5
// baseline (808.015 us; speedup 1.0000x reference)
//
#include <hip/hip_runtime.h>
#include <hip/hip_bf16.h>
#include <math.h>

#define B_    8
#define N_    1024
#define D_    1024
#define H_    16
#define DH_   64
#define HID_  4096
#define KD_   512
#define ROWS_ 8192
#define GTOT  4194304u

typedef _Float16 half8 __attribute__((ext_vector_type(8)));
typedef _Float16 half4v __attribute__((ext_vector_type(4)));
typedef float f32x4 __attribute__((ext_vector_type(4)));

// ---------------- reductions ----------------
__device__ __forceinline__ float waveSum(float v) {
#pragma unroll
  for (int off = 32; off > 0; off >>= 1) v += __shfl_down(v, off, 64);
  return v;
}
__device__ __forceinline__ float waveMax(float v) {
#pragma unroll
  for (int off = 32; off > 0; off >>= 1) v = fmaxf(v, __shfl_down(v, off, 64));
  return v;
}

// ---------------- threefry2x32, key=(0,42) ----------------
__device__ __forceinline__ uint32_t rotl32(uint32_t x, int r) { return (x << r) | (x >> (32 - r)); }

__device__ __forceinline__ void threefry_0_42(uint32_t& x0, uint32_t& x1) {
  const uint32_t ks0 = 0u, ks1 = 42u, ks2 = 0x1BD11BDAu ^ 42u;
#define TF_R(r) { x0 += x1; x1 = rotl32(x1, r); x1 ^= x0; }
  x0 += ks0; x1 += ks1;
  TF_R(13) TF_R(15) TF_R(26) TF_R(6)   x0 += ks1; x1 += ks2 + 1u;
  TF_R(17) TF_R(29) TF_R(16) TF_R(24)  x0 += ks2; x1 += ks0 + 2u;
  TF_R(13) TF_R(15) TF_R(26) TF_R(6)   x0 += ks0; x1 += ks1 + 3u;
  TF_R(17) TF_R(29) TF_R(16) TF_R(24)  x0 += ks1; x1 += ks2 + 4u;
  TF_R(13) TF_R(15) TF_R(26) TF_R(6)   x0 += ks2; x1 += ks0 + 5u;
#undef TF_R
}

__device__ __forceinline__ float bits_to_gumbel(uint32_t bits) {
  const float TINY = 1.1754943508222875e-38f;
  float u = __uint_as_float((bits >> 9) | 0x3f800000u) - 1.0f;
  u = u + TINY;
  u = fmaxf(TINY, u);
  return -logf(-logf(u));
}

// jax_threefry_partitionable: bits[j] = y0^y1 of threefry_{0,42}(0, j)
__global__ __launch_bounds__(256) void gumbel_kernel(float* __restrict__ g) {
  const unsigned j = blockIdx.x * 256u + threadIdx.x;
  uint32_t x0 = 0u, x1 = j;
  threefry_0_42(x0, x1);
  g[j] = bits_to_gumbel(x0 ^ x1);
}

// ---------------- fp32 -> fp16 conversion ----------------
__global__ __launch_bounds__(256) void f2h_kernel(const float* __restrict__ in,
                                                  _Float16* __restrict__ out, int n4) {
  const int i = blockIdx.x * 256 + threadIdx.x;
  if (i < n4) {
    const float4 v = reinterpret_cast<const float4*>(in)[i];
    half4v h;
    h[0] = (_Float16)v.x; h[1] = (_Float16)v.y; h[2] = (_Float16)v.z; h[3] = (_Float16)v.w;
    reinterpret_cast<half4v*>(out)[i] = h;
  }
}

// ---------------- LayerNorm -> fp16 out ----------------
__global__ __launch_bounds__(256) void ln_kernel(const float* __restrict__ in,
                                                 const float* __restrict__ w,
                                                 const float* __restrict__ b,
                                                 _Float16* __restrict__ out) {
  __shared__ float sh[4];
  const int row = blockIdx.x;
  const int tid = threadIdx.x;
  const float4 v = reinterpret_cast<const float4*>(in + (size_t)row * D_)[tid];
  float s = v.x + v.y + v.z + v.w;
  s = waveSum(s);
  if ((tid & 63) == 0) sh[tid >> 6] = s;
  __syncthreads();
  const float mean = (sh[0] + sh[1] + sh[2] + sh[3]) * (1.0f / D_);
  __syncthreads();
  const float dx = v.x - mean, dy = v.y - mean, dz = v.z - mean, dw = v.w - mean;
  float q = dx * dx + dy * dy + dz * dz + dw * dw;
  q = waveSum(q);
  if ((tid & 63) == 0) sh[tid >> 6] = q;
  __syncthreads();
  const float rstd = rsqrtf((sh[0] + sh[1] + sh[2] + sh[3]) * (1.0f / D_) + 1e-5f);
  const float4 wv = reinterpret_cast<const float4*>(w)[tid];
  const float4 bv = reinterpret_cast<const float4*>(b)[tid];
  half4v o;
  o[0] = (_Float16)(dx * rstd * wv.x + bv.x);
  o[1] = (_Float16)(dy * rstd * wv.y + bv.y);
  o[2] = (_Float16)(dz * rstd * wv.z + bv.z);
  o[3] = (_Float16)(dw * rstd * wv.w + bv.w);
  reinterpret_cast<half4v*>(out + (size_t)row * D_)[tid] = o;
}

// ---------------- fp16 MFMA GEMM, BM=BMF*16 x BN=BNF*16 tile, BK=32, 512 thr / 8 waves ----------------
// Wave grid 2(M) x 4(N). Fragment-linear LDS, global_load_lds 16B, 1 barrier / K-step.
#define GLDS16(g, l)                                                             \
  __builtin_amdgcn_global_load_lds((const __attribute__((address_space(1))) void*)(g), \
                                   (__attribute__((address_space(3))) void*)(l), 16, 0, 0)

template <int BMF, int BNF, bool GELU_EP, bool RES, bool OUT_HALF>
__global__ __launch_bounds__(512) void hgemm2_kernel(const _Float16* __restrict__ A,
                                                     const _Float16* __restrict__ W,
                                                     const float* __restrict__ bias,
                                                     const float* __restrict__ res,
                                                     void* __restrict__ Cout,
                                                     int Nn, int K, int nbx) {
  constexpr int WMF = BMF / 2;      // frags per wave (M)
  constexpr int WNF = BNF / 4;      // frags per wave (N)
  constexpr int TA = BMF / 8;       // A-frag stage rounds per wave
  constexpr int TB = BNF / 8;       // B-frag stage rounds per wave
  __shared__ __align__(16) _Float16 As[2][BMF * 512];
  __shared__ __align__(16) _Float16 Bs[2][BNF * 512];

  const int tid = threadIdx.x;
  const int lane = tid & 63;
  const int wv = tid >> 6;          // 0..7
  const int wr = wv >> 2, wc = wv & 3;

  // bijective XCD swizzle (grids here are multiples of 8)
  const int nwg = (int)gridDim.x;
  const int q8 = nwg >> 3, r8 = nwg & 7;
  const int x = (int)blockIdx.x & 7, idx = (int)blockIdx.x >> 3;
  const int wg = (x < r8 ? x * (q8 + 1) : r8 * (q8 + 1) + (x - r8) * q8) + idx;
  const int m0 = (wg / nbx) * (BMF * 16), n0 = (wg % nbx) * (BNF * 16);

  const int fr = lane & 15;
  const int k8 = (lane >> 4) << 3;

  f32x4 acc[WMF][WNF];
#pragma unroll
  for (int i = 0; i < WMF; ++i)
#pragma unroll
    for (int j = 0; j < WNF; ++j) acc[i][j] = (f32x4)0.0f;

  const int KT = K >> 5;

  // prologue: stage tile 0 into buf 0
#pragma unroll
  for (int t = 0; t < TA; ++t) {
    const int f = t * 8 + wv;
    GLDS16(A + (size_t)(m0 + f * 16 + fr) * K + k8, &As[0][f * 512]);
  }
#pragma unroll
  for (int t = 0; t < TB; ++t) {
    const int f = t * 8 + wv;
    GLDS16(W + (size_t)(n0 + f * 16 + fr) * K + k8, &Bs[0][f * 512]);
  }

  int buf = 0;
  for (int kt = 0; kt < KT; ++kt) {
    __syncthreads();   // drains vmcnt: tile kt staged; prev reads of buf^1 done
    if (kt + 1 < KT) {
      const int k0 = (kt + 1) << 5;
#pragma unroll
      for (int t = 0; t < TA; ++t) {
        const int f = t * 8 + wv;
        GLDS16(A + (size_t)(m0 + f * 16 + fr) * K + k0 + k8, &As[buf ^ 1][f * 512]);
      }
#pragma unroll
      for (int t = 0; t < TB; ++t) {
        const int f = t * 8 + wv;
        GLDS16(W + (size_t)(n0 + f * 16 + fr) * K + k0 + k8, &Bs[buf ^ 1][f * 512]);
      }
    }
    half8 af[WMF], bf[WNF];
#pragma unroll
    for (int i = 0; i < WMF; ++i)
      af[i] = *reinterpret_cast<const half8*>(&As[buf][(wr * WMF + i) * 512 + lane * 8]);
#pragma unroll
    for (int j = 0; j < WNF; ++j)
      bf[j] = *reinterpret_cast<const half8*>(&Bs[buf][(wc * WNF + j) * 512 + lane * 8]);
#pragma unroll
    for (int i = 0; i < WMF; ++i)
#pragma unroll
      for (int j = 0; j < WNF; ++j)
        acc[i][j] = __builtin_amdgcn_mfma_f32_16x16x32_f16(af[i], bf[j], acc[i][j], 0, 0, 0);
    buf ^= 1;
  }

  // epilogue: C/D layout col=lane&15, row=(lane>>4)*4+reg
  float bv[WNF];
#pragma unroll
  for (int j = 0; j < WNF; ++j) bv[j] = bias[n0 + (wc * WNF + j) * 16 + fr];
#pragma unroll
  for (int i = 0; i < WMF; ++i) {
#pragma unroll
    for (int r = 0; r < 4; ++r) {
      const int row = m0 + (wr * WMF + i) * 16 + ((lane >> 4) << 2) + r;
      const size_t ro = (size_t)row * Nn;
#pragma unroll
      for (int j = 0; j < WNF; ++j) {
        const int col = n0 + (wc * WNF + j) * 16 + fr;
        float u = acc[i][j][r] + bv[j];
        if (GELU_EP) u = 0.5f * u * (1.0f + erff(u * 0.70710678118654752f));
        if (RES) u += res[ro + col];
        if (OUT_HALF) ((_Float16*)Cout)[ro + col] = (_Float16)u;
        else          ((float*)Cout)[ro + col] = u;
      }
    }
  }
}

// ---------------- MFMA flash attention (fp16 in/out, fp32 softmax/acc) ----------------
__global__ __launch_bounds__(256) void mattn_kernel(const _Float16* __restrict__ qkv,
                                                    _Float16* __restrict__ ctx) {
  __shared__ __align__(16) _Float16 Ks[64][72];
  __shared__ __align__(16) _Float16 Vt[64][72];
  __shared__ __align__(16) _Float16 Ps[4][16][72];
  const int qt = blockIdx.x, h = blockIdx.y, b = blockIdx.z;
  const int tid = threadIdx.x;
  const int lane = tid & 63;
  const int w = tid >> 6;
  const int l15 = lane & 15;
  const int koff = (lane >> 4) * 8;

  const size_t qrow = (size_t)b * N_ + qt * 64 + w * 16 + l15;
  half8 qf0 = *reinterpret_cast<const half8*>(qkv + qrow * 3072 + h * 64 + koff);
  half8 qf1 = *reinterpret_cast<const half8*>(qkv + qrow * 3072 + h * 64 + 32 + koff);

  const int skey = tid >> 2;
  const int sch = (tid & 3) * 16;

  float m_i[4], l_i[4];
  f32x4 oacc[4];
#pragma unroll
  for (int r = 0; r < 4; ++r) { m_i[r] = -3.0e38f; l_i[r] = 0.0f; }
#pragma unroll
  for (int jb = 0; jb < 4; ++jb) oacc[jb] = (f32x4)0.0f;

  for (int kt = 0; kt < 16; ++kt) {
    __syncthreads();
    const _Float16* krow = qkv + ((size_t)b * N_ + kt * 64 + skey) * 3072 + 1024 + h * 64 + sch;
    half8 k0 = *reinterpret_cast<const half8*>(krow);
    half8 k1 = *reinterpret_cast<const half8*>(krow + 8);
    half8 v0 = *reinterpret_cast<const half8*>(krow + 1024);
    half8 v1 = *reinterpret_cast<const half8*>(krow + 1032);
    *reinterpret_cast<half8*>(&Ks[skey][sch]) = k0;
    *reinterpret_cast<half8*>(&Ks[skey][sch + 8]) = k1;
#pragma unroll
    for (int j = 0; j < 8; ++j) {
      Vt[sch + j][skey] = v0[j];
      Vt[sch + 8 + j][skey] = v1[j];
    }
    __syncthreads();

    f32x4 sacc[4];
#pragma unroll
    for (int jb = 0; jb < 4; ++jb) sacc[jb] = (f32x4)0.0f;
#pragma unroll
    for (int jb = 0; jb < 4; ++jb) {
      half8 kfa = *reinterpret_cast<const half8*>(&Ks[jb * 16 + l15][koff]);
      half8 kfb = *reinterpret_cast<const half8*>(&Ks[jb * 16 + l15][32 + koff]);
      sacc[jb] = __builtin_amdgcn_mfma_f32_16x16x32_f16(qf0, kfa, sacc[jb], 0, 0, 0);
      sacc[jb] = __builtin_amdgcn_mfma_f32_16x16x32_f16(qf1, kfb, sacc[jb], 0, 0, 0);
    }

    float p[4][4];
#pragma unroll
    for (int jb = 0; jb < 4; ++jb)
#pragma unroll
      for (int r = 0; r < 4; ++r) sacc[jb][r] *= 0.125f;
#pragma unroll
    for (int r = 0; r < 4; ++r) {
      float mx = fmaxf(fmaxf(sacc[0][r], sacc[1][r]), fmaxf(sacc[2][r], sacc[3][r]));
#pragma unroll
      for (int mk = 1; mk < 16; mk <<= 1) mx = fmaxf(mx, __shfl_xor(mx, mk, 64));
      const float nm = fmaxf(m_i[r], mx);
      const float scale = expf(m_i[r] - nm);
      float rs = 0.0f;
#pragma unroll
      for (int jb = 0; jb < 4; ++jb) { p[jb][r] = expf(sacc[jb][r] - nm); rs += p[jb][r]; }
#pragma unroll
      for (int mk = 1; mk < 16; mk <<= 1) rs += __shfl_xor(rs, mk, 64);
      l_i[r] = l_i[r] * scale + rs;
      m_i[r] = nm;
#pragma unroll
      for (int jb = 0; jb < 4; ++jb) oacc[jb][r] *= scale;
    }

#pragma unroll
    for (int jb = 0; jb < 4; ++jb)
#pragma unroll
      for (int r = 0; r < 4; ++r)
        Ps[w][(lane >> 4) * 4 + r][jb * 16 + l15] = (_Float16)p[jb][r];

    half8 pf0 = *reinterpret_cast<const half8*>(&Ps[w][l15][koff]);
    half8 pf1 = *reinterpret_cast<const half8*>(&Ps[w][l15][32 + koff]);
#pragma unroll
    for (int jb = 0; jb < 4; ++jb) {
      half8 vf0 = *reinterpret_cast<const half8*>(&Vt[jb * 16 + l15][koff]);
      half8 vf1 = *reinterpret_cast<const half8*>(&Vt[jb * 16 + l15][32 + koff]);
      oacc[jb] = __builtin_amdgcn_mfma_f32_16x16x32_f16(pf0, vf0, oacc[jb], 0, 0, 0);
      oacc[jb] = __builtin_amdgcn_mfma_f32_16x16x32_f16(pf1, vf1, oacc[jb], 0, 0, 0);
    }
  }

#pragma unroll
  for (int jb = 0; jb < 4; ++jb)
#pragma unroll
    for (int r = 0; r < 4; ++r) {
      const size_t orow = (size_t)b * N_ + qt * 64 + w * 16 + (lane >> 4) * 4 + r;
      ctx[orow * 1024 + h * 64 + jb * 16 + l15] = (_Float16)(oacc[jb][r] / l_i[r]);
    }
}

// ---------------- score ----------------
__global__ __launch_bounds__(256) void score_kernel(const float* __restrict__ hbuf,
                                                    const float* __restrict__ lw,
                                                    float* __restrict__ mp) {
  __shared__ float sh[4];
  const int row = blockIdx.x, tid = threadIdx.x;
  const float4 v = reinterpret_cast<const float4*>(hbuf + (size_t)row * D_)[tid];
  const float4 w = reinterpret_cast<const float4*>(lw)[tid];
  float s = v.x * w.x + v.y * w.y + v.z * w.z + v.w * w.w;
  s = waveSum(s);
  if ((tid & 63) == 0) sh[tid >> 6] = s;
  __syncthreads();
  if (tid == 0) mp[row] = sh[0] + sh[1] + sh[2] + sh[3];
}

// ---------------- lse over n of 2*(mp+g) ----------------
__global__ __launch_bounds__(256) void lse_kernel(const float* __restrict__ g,
                                                  const float* __restrict__ mp,
                                                  float* __restrict__ lse) {
  __shared__ float sh[4];
  const int row = blockIdx.x;          // k*8+b
  const int b = row & 7;
  const int tid = threadIdx.x;
  const float4 gv = reinterpret_cast<const float4*>(g + (size_t)row * 1024)[tid];
  const float4 mv = reinterpret_cast<const float4*>(mp + b * 1024)[tid];
  const float l0 = 2.0f * (gv.x + mv.x), l1 = 2.0f * (gv.y + mv.y);
  const float l2 = 2.0f * (gv.z + mv.z), l3 = 2.0f * (gv.w + mv.w);
  float mx = fmaxf(fmaxf(l0, l1), fmaxf(l2, l3));
  mx = waveMax(mx);
  if ((tid & 63) == 0) sh[tid >> 6] = mx;
  __syncthreads();
  mx = fmaxf(fmaxf(sh[0], sh[1]), fmaxf(sh[2], sh[3]));
  __syncthreads();
  float se = expf(l0 - mx) + expf(l1 - mx) + expf(l2 - mx) + expf(l3 - mx);
  se = waveSum(se);
  if ((tid & 63) == 0) sh[tid >> 6] = se;
  __syncthreads();
  if (tid == 0) lse[row] = mx + logf(sh[0] + sh[1] + sh[2] + sh[3]);
}

// ---------------- z ----------------
__global__ __launch_bounds__(256) void z_kernel(const float* __restrict__ g,
                                                const float* __restrict__ mp,
                                                const float* __restrict__ lse,
                                                float* __restrict__ z) {
  const int idx = blockIdx.x * 256 + threadIdx.x;
  const int b = idx >> 10;
  float best = -3.0e38f;
#pragma unroll 8
  for (int k = 0; k < KD_; ++k) {
    const float gv = g[(size_t)k * ROWS_ + idx];
    best = fmaxf(best, 2.0f * gv - lse[k * 8 + b]);
  }
  z[idx] = expf(2.0f * mp[idx] + best);
}

extern "C" void kernel_launch(void* const* d_in, const int* in_sizes, int n_in,
                              void* d_out, int out_size, void* d_ws, size_t ws_size,
                              hipStream_t stream) {
  (void)in_sizes; (void)n_in; (void)out_size; (void)ws_size;
  const float* f      = (const float*)d_in[0];
  const float* qkv_w  = (const float*)d_in[2];
  const float* qkv_b  = (const float*)d_in[3];
  const float* proj_w = (const float*)d_in[4];
  const float* proj_b = (const float*)d_in[5];
  const float* ln1_w  = (const float*)d_in[6];
  const float* ln1_b  = (const float*)d_in[7];
  const float* ln2_w  = (const float*)d_in[8];
  const float* ln2_b  = (const float*)d_in[9];
  const float* fc1_w  = (const float*)d_in[10];
  const float* fc1_b  = (const float*)d_in[11];
  const float* fc2_w  = (const float*)d_in[12];
  const float* fc2_b  = (const float*)d_in[13];
  const float* lin_w  = (const float*)d_in[14];
  float* out = (float*)d_out;

  // -------- workspace (f32 offsets; peak 44,052,480 f32 = 176 MB) --------
  float* ws = (float*)d_ws;
  _Float16* wh = (_Float16*)d_ws;
  _Float16* QKVWH  = wh;                        // 3,145,728 h
  _Float16* PROJWH = wh + 3145728;              // 1,048,576 h
  _Float16* FC1WH  = wh + 4194304;              // 4,194,304 h
  _Float16* FC2WH  = wh + 8388608;              // 4,194,304 h -> ends f32 6,291,456
  float* MP  = ws + 6291456;                    // 8192
  float* LSE = ws + 6299648;                    // 4096
  _Float16* XH   = (_Float16*)(ws + 6303744);   // 8,388,608 h
  _Float16* QKVH = (_Float16*)(ws + 10498048);  // 25,165,824 h (dead after attn)
  _Float16* CTXH = (_Float16*)(ws + 23080960);  // 8,388,608 h
  _Float16* YH   = (_Float16*)(ws + 10498048);  // 16,777,216 h (reuses QKVH)
  float* F1   = ws + 27275264;                  // 8,388,608 f32
  float* Hbuf = ws + 35663872;                  // 8,388,608 f32 -> end 44,052,480
  float* G    = ws;                             // 4,194,304 f32 (weights dead by then)

  f2h_kernel<<<3072, 256, 0, stream>>>(qkv_w, QKVWH, 786432);
  f2h_kernel<<<1024, 256, 0, stream>>>(proj_w, PROJWH, 262144);
  f2h_kernel<<<4096, 256, 0, stream>>>(fc1_w, FC1WH, 1048576);
  f2h_kernel<<<4096, 256, 0, stream>>>(fc2_w, FC2WH, 1048576);

  ln_kernel<<<ROWS_, 256, 0, stream>>>(f, ln1_w, ln1_b, XH);
  // qkv: M=8192 N=3072 K=1024, 256x256 tiles -> grid 32*12=384
  hgemm2_kernel<16, 16, false, false, true><<<384, 512, 0, stream>>>(XH, QKVWH, qkv_b, nullptr, QKVH, 3072, 1024, 12);
  mattn_kernel<<<dim3(16, 16, 8), 256, 0, stream>>>(QKVH, CTXH);
  // proj: M=8192 N=1024 K=1024, 128x256 tiles -> grid 64*4=256
  hgemm2_kernel<8, 16, false, true, false><<<256, 512, 0, stream>>>(CTXH, PROJWH, proj_b, f, F1, 1024, 1024, 4);
  ln_kernel<<<ROWS_, 256, 0, stream>>>(F1, ln2_w, ln2_b, XH);
  // fc1: M=8192 N=4096 K=1024, 256x256 tiles -> grid 32*16=512
  hgemm2_kernel<16, 16, true, false, true><<<512, 512, 0, stream>>>(XH, FC1WH, fc1_b, nullptr, YH, 4096, 1024, 16);
  // fc2: M=8192 N=1024 K=4096, 128x256 tiles -> grid 64*4=256
  hgemm2_kernel<8, 16, false, true, false><<<256, 512, 0, stream>>>(YH, FC2WH, fc2_b, F1, Hbuf, 1024, 4096, 4);
  score_kernel<<<ROWS_, 256, 0, stream>>>(Hbuf, lin_w, MP);
  gumbel_kernel<<<GTOT / 256, 256, 0, stream>>>(G);
  lse_kernel<<<KD_ * B_, 256, 0, stream>>>(G, MP, LSE);
  z_kernel<<<ROWS_ / 256, 256, 0, stream>>>(G, MP, LSE, out);
}

// Round 6
// 709.295 us; speedup vs baseline: 1.1392x; 1.1392x over previous
//
#include <hip/hip_runtime.h>
#include <hip/hip_bf16.h>
#include <math.h>

#define B_    8
#define N_    1024
#define D_    1024
#define H_    16
#define DH_   64
#define HID_  4096
#define KD_   512
#define ROWS_ 8192
#define GTOT  4194304u

typedef _Float16 half8 __attribute__((ext_vector_type(8)));
typedef _Float16 half4v __attribute__((ext_vector_type(4)));
typedef float f32x4 __attribute__((ext_vector_type(4)));

// ---------------- reductions ----------------
__device__ __forceinline__ float waveSum(float v) {
#pragma unroll
  for (int off = 32; off > 0; off >>= 1) v += __shfl_down(v, off, 64);
  return v;
}
__device__ __forceinline__ float waveMax(float v) {
#pragma unroll
  for (int off = 32; off > 0; off >>= 1) v = fmaxf(v, __shfl_down(v, off, 64));
  return v;
}

// ---------------- threefry2x32, key=(0,42) ----------------
__device__ __forceinline__ uint32_t rotl32(uint32_t x, int r) { return (x << r) | (x >> (32 - r)); }

__device__ __forceinline__ void threefry_0_42(uint32_t& x0, uint32_t& x1) {
  const uint32_t ks0 = 0u, ks1 = 42u, ks2 = 0x1BD11BDAu ^ 42u;
#define TF_R(r) { x0 += x1; x1 = rotl32(x1, r); x1 ^= x0; }
  x0 += ks0; x1 += ks1;
  TF_R(13) TF_R(15) TF_R(26) TF_R(6)   x0 += ks1; x1 += ks2 + 1u;
  TF_R(17) TF_R(29) TF_R(16) TF_R(24)  x0 += ks2; x1 += ks0 + 2u;
  TF_R(13) TF_R(15) TF_R(26) TF_R(6)   x0 += ks0; x1 += ks1 + 3u;
  TF_R(17) TF_R(29) TF_R(16) TF_R(24)  x0 += ks1; x1 += ks2 + 4u;
  TF_R(13) TF_R(15) TF_R(26) TF_R(6)   x0 += ks2; x1 += ks0 + 5u;
#undef TF_R
}

__device__ __forceinline__ float bits_to_gumbel(uint32_t bits) {
  const float TINY = 1.1754943508222875e-38f;
  float u = __uint_as_float((bits >> 9) | 0x3f800000u) - 1.0f;
  u = u + TINY;
  u = fmaxf(TINY, u);
  return -logf(-logf(u));
}

// jax_threefry_partitionable: bits[j] = y0^y1 of threefry_{0,42}(0, j)
__global__ __launch_bounds__(256) void gumbel_kernel(float* __restrict__ g) {
  const unsigned j = blockIdx.x * 256u + threadIdx.x;
  uint32_t x0 = 0u, x1 = j;
  threefry_0_42(x0, x1);
  g[j] = bits_to_gumbel(x0 ^ x1);
}

// ---------------- fp32 -> fp16 conversion ----------------
__global__ __launch_bounds__(256) void f2h_kernel(const float* __restrict__ in,
                                                  _Float16* __restrict__ out, int n4) {
  const int i = blockIdx.x * 256 + threadIdx.x;
  if (i < n4) {
    const float4 v = reinterpret_cast<const float4*>(in)[i];
    half4v h;
    h[0] = (_Float16)v.x; h[1] = (_Float16)v.y; h[2] = (_Float16)v.z; h[3] = (_Float16)v.w;
    reinterpret_cast<half4v*>(out)[i] = h;
  }
}

// ---------------- LayerNorm -> fp16 out ----------------
__global__ __launch_bounds__(256) void ln_kernel(const float* __restrict__ in,
                                                 const float* __restrict__ w,
                                                 const float* __restrict__ b,
                                                 _Float16* __restrict__ out) {
  __shared__ float sh[4];
  const int row = blockIdx.x;
  const int tid = threadIdx.x;
  const float4 v = reinterpret_cast<const float4*>(in + (size_t)row * D_)[tid];
  float s = v.x + v.y + v.z + v.w;
  s = waveSum(s);
  if ((tid & 63) == 0) sh[tid >> 6] = s;
  __syncthreads();
  const float mean = (sh[0] + sh[1] + sh[2] + sh[3]) * (1.0f / D_);
  __syncthreads();
  const float dx = v.x - mean, dy = v.y - mean, dz = v.z - mean, dw = v.w - mean;
  float q = dx * dx + dy * dy + dz * dz + dw * dw;
  q = waveSum(q);
  if ((tid & 63) == 0) sh[tid >> 6] = q;
  __syncthreads();
  const float rstd = rsqrtf((sh[0] + sh[1] + sh[2] + sh[3]) * (1.0f / D_) + 1e-5f);
  const float4 wv = reinterpret_cast<const float4*>(w)[tid];
  const float4 bv = reinterpret_cast<const float4*>(b)[tid];
  half4v o;
  o[0] = (_Float16)(dx * rstd * wv.x + bv.x);
  o[1] = (_Float16)(dy * rstd * wv.y + bv.y);
  o[2] = (_Float16)(dz * rstd * wv.z + bv.z);
  o[3] = (_Float16)(dw * rstd * wv.w + bv.w);
  reinterpret_cast<half4v*>(out + (size_t)row * D_)[tid] = o;
}

// ---------------- fast GELU: A&S 7.1.26 erf approx, max err 1.5e-7 ----------------
__device__ __forceinline__ float fast_gelu(float x) {
  const float z = fabsf(x) * 0.70710678118654752f;
  const float t = 1.0f / (1.0f + 0.3275911f * z);
  const float poly = t * (0.254829592f + t * (-0.284496736f +
                      t * (1.421413741f + t * (-1.453152027f + t * 1.061405429f))));
  float erfz = 1.0f - poly * __expf(-z * z);
  erfz = copysignf(erfz, x);
  return 0.5f * x * (1.0f + erfz);
}

// ---------------- fp16 MFMA GEMM: 128x128 tile, BK=32, 256 thr / 4 waves ----------------
// 3 LDS buffers, 2-tiles-ahead prefetch, counted vmcnt (never 0 in steady loop).
#define GLDS16(g, l)                                                             \
  __builtin_amdgcn_global_load_lds((const __attribute__((address_space(1))) void*)(g), \
                                   (__attribute__((address_space(3))) void*)(l), 16, 0, 0)

template <bool GELU_EP, bool RES, bool OUT_HALF>
__global__ __launch_bounds__(256) void hgemm_kernel(const _Float16* __restrict__ A,
                                                    const _Float16* __restrict__ W,
                                                    const float* __restrict__ bias,
                                                    const float* __restrict__ res,
                                                    void* __restrict__ Cout,
                                                    int Nn, int K, int nbx) {
  __shared__ __align__(16) _Float16 As[3][4096];   // 8 frags x 512 fp16 per buffer
  __shared__ __align__(16) _Float16 Bs[3][4096];

  const int tid = threadIdx.x;
  const int lane = tid & 63;
  const int wv = tid >> 6;
  const int wr = wv >> 1, wc = wv & 1;

  // bijective XCD swizzle (grids are multiples of 8)
  const int nwg = (int)gridDim.x;
  const int q8 = nwg >> 3, r8 = nwg & 7;
  const int x = (int)blockIdx.x & 7, idx = (int)blockIdx.x >> 3;
  const int wg = (x < r8 ? x * (q8 + 1) : r8 * (q8 + 1) + (x - r8) * q8) + idx;
  const int m0 = (wg / nbx) * 128, n0 = (wg % nbx) * 128;

  const int fr = lane & 15;
  const int k8 = (lane >> 4) << 3;

  f32x4 acc[4][4];
#pragma unroll
  for (int i = 0; i < 4; ++i)
#pragma unroll
    for (int j = 0; j < 4; ++j) acc[i][j] = (f32x4)0.0f;

  const int KT = K >> 5;   // >= 32 for all our shapes

#define STAGE(bi, ktile)                                                              \
  {                                                                                   \
    const int kq = (ktile) << 5;                                                      \
    _Float16* asb = &As[bi][0];                                                       \
    _Float16* bsb = &Bs[bi][0];                                                       \
    _Pragma("unroll")                                                                 \
    for (int t2 = 0; t2 < 2; ++t2) {                                                  \
      const int ff = wv * 2 + t2;                                                     \
      GLDS16(A + (size_t)(m0 + ff * 16 + fr) * K + kq + k8, asb + ff * 512);          \
      GLDS16(W + (size_t)(n0 + ff * 16 + fr) * K + kq + k8, bsb + ff * 512);          \
    }                                                                                 \
  }

  // prologue: tiles 0 and 1 in flight (8 loads/thread outstanding)
  STAGE(0, 0);
  STAGE(1, 1);

  for (int kt = 0; kt < KT; ++kt) {
    // tile kt's 4 loads (oldest) must be complete; keep tile kt+1's 4 in flight.
    if (kt < KT - 1) asm volatile("s_waitcnt vmcnt(4)" ::: "memory");
    else             asm volatile("s_waitcnt vmcnt(0)" ::: "memory");
    __builtin_amdgcn_s_barrier();   // collective: ALL waves' tile-kt loads done
    if (kt + 2 < KT) { STAGE((kt + 2) % 3, kt + 2); }
    const int bc = kt % 3;
    half8 af[4], bf[4];
#pragma unroll
    for (int i = 0; i < 4; ++i)
      af[i] = *reinterpret_cast<const half8*>(&As[bc][(wr * 4 + i) * 512 + lane * 8]);
#pragma unroll
    for (int j = 0; j < 4; ++j)
      bf[j] = *reinterpret_cast<const half8*>(&Bs[bc][(wc * 4 + j) * 512 + lane * 8]);
#pragma unroll
    for (int i = 0; i < 4; ++i)
#pragma unroll
      for (int j = 0; j < 4; ++j)
        acc[i][j] = __builtin_amdgcn_mfma_f32_16x16x32_f16(af[i], bf[j], acc[i][j], 0, 0, 0);
    // wave may not reach next barrier with LDS reads of buf[bc] still in flight:
    asm volatile("s_waitcnt lgkmcnt(0)" ::: "memory");
  }
#undef STAGE

  // epilogue: C/D layout col=lane&15, row=(lane>>4)*4+reg
  float bv[4];
#pragma unroll
  for (int j = 0; j < 4; ++j) bv[j] = bias[n0 + (wc * 4 + j) * 16 + fr];
#pragma unroll
  for (int i = 0; i < 4; ++i) {
#pragma unroll
    for (int r = 0; r < 4; ++r) {
      const int row = m0 + (wr * 4 + i) * 16 + ((lane >> 4) << 2) + r;
      const size_t ro = (size_t)row * Nn;
#pragma unroll
      for (int j = 0; j < 4; ++j) {
        const int col = n0 + (wc * 4 + j) * 16 + fr;
        float u = acc[i][j][r] + bv[j];
        if (GELU_EP) u = fast_gelu(u);
        if (RES) u += res[ro + col];
        if (OUT_HALF) ((_Float16*)Cout)[ro + col] = (_Float16)u;
        else          ((float*)Cout)[ro + col] = u;
      }
    }
  }
}

// ---------------- MFMA flash attention (fp16 in/out, fp32 softmax/acc) ----------------
__global__ __launch_bounds__(256) void mattn_kernel(const _Float16* __restrict__ qkv,
                                                    _Float16* __restrict__ ctx) {
  __shared__ __align__(16) _Float16 Ks[64][72];
  __shared__ __align__(16) _Float16 Vt[64][72];
  __shared__ __align__(16) _Float16 Ps[4][16][72];
  const int qt = blockIdx.x, h = blockIdx.y, b = blockIdx.z;
  const int tid = threadIdx.x;
  const int lane = tid & 63;
  const int w = tid >> 6;
  const int l15 = lane & 15;
  const int koff = (lane >> 4) * 8;

  const size_t qrow = (size_t)b * N_ + qt * 64 + w * 16 + l15;
  half8 qf0 = *reinterpret_cast<const half8*>(qkv + qrow * 3072 + h * 64 + koff);
  half8 qf1 = *reinterpret_cast<const half8*>(qkv + qrow * 3072 + h * 64 + 32 + koff);

  const int skey = tid >> 2;
  const int sch = (tid & 3) * 16;

  float m_i[4], l_i[4];
  f32x4 oacc[4];
#pragma unroll
  for (int r = 0; r < 4; ++r) { m_i[r] = -3.0e38f; l_i[r] = 0.0f; }
#pragma unroll
  for (int jb = 0; jb < 4; ++jb) oacc[jb] = (f32x4)0.0f;

  for (int kt = 0; kt < 16; ++kt) {
    __syncthreads();
    const _Float16* krow = qkv + ((size_t)b * N_ + kt * 64 + skey) * 3072 + 1024 + h * 64 + sch;
    half8 k0 = *reinterpret_cast<const half8*>(krow);
    half8 k1 = *reinterpret_cast<const half8*>(krow + 8);
    half8 v0 = *reinterpret_cast<const half8*>(krow + 1024);
    half8 v1 = *reinterpret_cast<const half8*>(krow + 1032);
    *reinterpret_cast<half8*>(&Ks[skey][sch]) = k0;
    *reinterpret_cast<half8*>(&Ks[skey][sch + 8]) = k1;
#pragma unroll
    for (int j = 0; j < 8; ++j) {
      Vt[sch + j][skey] = v0[j];
      Vt[sch + 8 + j][skey] = v1[j];
    }
    __syncthreads();

    f32x4 sacc[4];
#pragma unroll
    for (int jb = 0; jb < 4; ++jb) sacc[jb] = (f32x4)0.0f;
#pragma unroll
    for (int jb = 0; jb < 4; ++jb) {
      half8 kfa = *reinterpret_cast<const half8*>(&Ks[jb * 16 + l15][koff]);
      half8 kfb = *reinterpret_cast<const half8*>(&Ks[jb * 16 + l15][32 + koff]);
      sacc[jb] = __builtin_amdgcn_mfma_f32_16x16x32_f16(qf0, kfa, sacc[jb], 0, 0, 0);
      sacc[jb] = __builtin_amdgcn_mfma_f32_16x16x32_f16(qf1, kfb, sacc[jb], 0, 0, 0);
    }

    float p[4][4];
#pragma unroll
    for (int jb = 0; jb < 4; ++jb)
#pragma unroll
      for (int r = 0; r < 4; ++r) sacc[jb][r] *= 0.125f;
#pragma unroll
    for (int r = 0; r < 4; ++r) {
      float mx = fmaxf(fmaxf(sacc[0][r], sacc[1][r]), fmaxf(sacc[2][r], sacc[3][r]));
#pragma unroll
      for (int mk = 1; mk < 16; mk <<= 1) mx = fmaxf(mx, __shfl_xor(mx, mk, 64));
      const float nm = fmaxf(m_i[r], mx);
      const float scale = expf(m_i[r] - nm);
      float rs = 0.0f;
#pragma unroll
      for (int jb = 0; jb < 4; ++jb) { p[jb][r] = expf(sacc[jb][r] - nm); rs += p[jb][r]; }
#pragma unroll
      for (int mk = 1; mk < 16; mk <<= 1) rs += __shfl_xor(rs, mk, 64);
      l_i[r] = l_i[r] * scale + rs;
      m_i[r] = nm;
#pragma unroll
      for (int jb = 0; jb < 4; ++jb) oacc[jb][r] *= scale;
    }

#pragma unroll
    for (int jb = 0; jb < 4; ++jb)
#pragma unroll
      for (int r = 0; r < 4; ++r)
        Ps[w][(lane >> 4) * 4 + r][jb * 16 + l15] = (_Float16)p[jb][r];

    half8 pf0 = *reinterpret_cast<const half8*>(&Ps[w][l15][koff]);
    half8 pf1 = *reinterpret_cast<const half8*>(&Ps[w][l15][32 + koff]);
#pragma unroll
    for (int jb = 0; jb < 4; ++jb) {
      half8 vf0 = *reinterpret_cast<const half8*>(&Vt[jb * 16 + l15][koff]);
      half8 vf1 = *reinterpret_cast<const half8*>(&Vt[jb * 16 + l15][32 + koff]);
      oacc[jb] = __builtin_amdgcn_mfma_f32_16x16x32_f16(pf0, vf0, oacc[jb], 0, 0, 0);
      oacc[jb] = __builtin_amdgcn_mfma_f32_16x16x32_f16(pf1, vf1, oacc[jb], 0, 0, 0);
    }
  }

#pragma unroll
  for (int jb = 0; jb < 4; ++jb)
#pragma unroll
    for (int r = 0; r < 4; ++r) {
      const size_t orow = (size_t)b * N_ + qt * 64 + w * 16 + (lane >> 4) * 4 + r;
      ctx[orow * 1024 + h * 64 + jb * 16 + l15] = (_Float16)(oacc[jb][r] / l_i[r]);
    }
}

// ---------------- score ----------------
__global__ __launch_bounds__(256) void score_kernel(const float* __restrict__ hbuf,
                                                    const float* __restrict__ lw,
                                                    float* __restrict__ mp) {
  __shared__ float sh[4];
  const int row = blockIdx.x, tid = threadIdx.x;
  const float4 v = reinterpret_cast<const float4*>(hbuf + (size_t)row * D_)[tid];
  const float4 w = reinterpret_cast<const float4*>(lw)[tid];
  float s = v.x * w.x + v.y * w.y + v.z * w.z + v.w * w.w;
  s = waveSum(s);
  if ((tid & 63) == 0) sh[tid >> 6] = s;
  __syncthreads();
  if (tid == 0) mp[row] = sh[0] + sh[1] + sh[2] + sh[3];
}

// ---------------- lse over n of 2*(mp+g) ----------------
__global__ __launch_bounds__(256) void lse_kernel(const float* __restrict__ g,
                                                  const float* __restrict__ mp,
                                                  float* __restrict__ lse) {
  __shared__ float sh[4];
  const int row = blockIdx.x;          // k*8+b
  const int b = row & 7;
  const int tid = threadIdx.x;
  const float4 gv = reinterpret_cast<const float4*>(g + (size_t)row * 1024)[tid];
  const float4 mv = reinterpret_cast<const float4*>(mp + b * 1024)[tid];
  const float l0 = 2.0f * (gv.x + mv.x), l1 = 2.0f * (gv.y + mv.y);
  const float l2 = 2.0f * (gv.z + mv.z), l3 = 2.0f * (gv.w + mv.w);
  float mx = fmaxf(fmaxf(l0, l1), fmaxf(l2, l3));
  mx = waveMax(mx);
  if ((tid & 63) == 0) sh[tid >> 6] = mx;
  __syncthreads();
  mx = fmaxf(fmaxf(sh[0], sh[1]), fmaxf(sh[2], sh[3]));
  __syncthreads();
  float se = expf(l0 - mx) + expf(l1 - mx) + expf(l2 - mx) + expf(l3 - mx);
  se = waveSum(se);
  if ((tid & 63) == 0) sh[tid >> 6] = se;
  __syncthreads();
  if (tid == 0) lse[row] = mx + logf(sh[0] + sh[1] + sh[2] + sh[3]);
}

// ---------------- z ----------------
__global__ __launch_bounds__(256) void z_kernel(const float* __restrict__ g,
                                                const float* __restrict__ mp,
                                                const float* __restrict__ lse,
                                                float* __restrict__ z) {
  const int idx = blockIdx.x * 256 + threadIdx.x;
  const int b = idx >> 10;
  float best = -3.0e38f;
#pragma unroll 8
  for (int k = 0; k < KD_; ++k) {
    const float gv = g[(size_t)k * ROWS_ + idx];
    best = fmaxf(best, 2.0f * gv - lse[k * 8 + b]);
  }
  z[idx] = expf(2.0f * mp[idx] + best);
}

extern "C" void kernel_launch(void* const* d_in, const int* in_sizes, int n_in,
                              void* d_out, int out_size, void* d_ws, size_t ws_size,
                              hipStream_t stream) {
  (void)in_sizes; (void)n_in; (void)out_size; (void)ws_size;
  const float* f      = (const float*)d_in[0];
  const float* qkv_w  = (const float*)d_in[2];
  const float* qkv_b  = (const float*)d_in[3];
  const float* proj_w = (const float*)d_in[4];
  const float* proj_b = (const float*)d_in[5];
  const float* ln1_w  = (const float*)d_in[6];
  const float* ln1_b  = (const float*)d_in[7];
  const float* ln2_w  = (const float*)d_in[8];
  const float* ln2_b  = (const float*)d_in[9];
  const float* fc1_w  = (const float*)d_in[10];
  const float* fc1_b  = (const float*)d_in[11];
  const float* fc2_w  = (const float*)d_in[12];
  const float* fc2_b  = (const float*)d_in[13];
  const float* lin_w  = (const float*)d_in[14];
  float* out = (float*)d_out;

  // -------- workspace (f32 offsets; peak 44,052,480 f32 = 176 MB) --------
  float* ws = (float*)d_ws;
  _Float16* wh = (_Float16*)d_ws;
  _Float16* QKVWH  = wh;                        // 3,145,728 h
  _Float16* PROJWH = wh + 3145728;              // 1,048,576 h
  _Float16* FC1WH  = wh + 4194304;              // 4,194,304 h
  _Float16* FC2WH  = wh + 8388608;              // 4,194,304 h -> ends f32 6,291,456
  float* MP  = ws + 6291456;                    // 8192
  float* LSE = ws + 6299648;                    // 4096
  _Float16* XH   = (_Float16*)(ws + 6303744);   // 8,388,608 h
  _Float16* QKVH = (_Float16*)(ws + 10498048);  // 25,165,824 h (dead after attn)
  _Float16* CTXH = (_Float16*)(ws + 23080960);  // 8,388,608 h
  _Float16* YH   = (_Float16*)(ws + 10498048);  // 16,777,216 h (reuses QKVH)
  float* F1   = ws + 27275264;                  // 8,388,608 f32
  float* Hbuf = ws + 35663872;                  // 8,388,608 f32 -> end 44,052,480
  float* G    = ws;                             // 4,194,304 f32 (weights dead by then)

  f2h_kernel<<<3072, 256, 0, stream>>>(qkv_w, QKVWH, 786432);
  f2h_kernel<<<1024, 256, 0, stream>>>(proj_w, PROJWH, 262144);
  f2h_kernel<<<4096, 256, 0, stream>>>(fc1_w, FC1WH, 1048576);
  f2h_kernel<<<4096, 256, 0, stream>>>(fc2_w, FC2WH, 1048576);

  ln_kernel<<<ROWS_, 256, 0, stream>>>(f, ln1_w, ln1_b, XH);
  hgemm_kernel<false, false, true><<<24 * 64, 256, 0, stream>>>(XH, QKVWH, qkv_b, nullptr, QKVH, 3072, 1024, 24);
  mattn_kernel<<<dim3(16, 16, 8), 256, 0, stream>>>(QKVH, CTXH);
  hgemm_kernel<false, true, false><<<8 * 64, 256, 0, stream>>>(CTXH, PROJWH, proj_b, f, F1, 1024, 1024, 8);
  ln_kernel<<<ROWS_, 256, 0, stream>>>(F1, ln2_w, ln2_b, XH);
  hgemm_kernel<true, false, true><<<32 * 64, 256, 0, stream>>>(XH, FC1WH, fc1_b, nullptr, YH, 4096, 1024, 32);
  hgemm_kernel<false, true, false><<<8 * 64, 256, 0, stream>>>(YH, FC2WH, fc2_b, F1, Hbuf, 1024, 4096, 8);
  score_kernel<<<ROWS_, 256, 0, stream>>>(Hbuf, lin_w, MP);
  gumbel_kernel<<<GTOT / 256, 256, 0, stream>>>(G);
  lse_kernel<<<KD_ * B_, 256, 0, stream>>>(G, MP, LSE);
  z_kernel<<<ROWS_ / 256, 256, 0, stream>>>(G, MP, LSE, out);
}

// Round 7
// 646.214 us; speedup vs baseline: 1.2504x; 1.0976x over previous
//
#include <hip/hip_runtime.h>
#include <hip/hip_bf16.h>
#include <math.h>

#define B_    8
#define N_    1024
#define D_    1024
#define H_    16
#define DH_   64
#define HID_  4096
#define KD_   512
#define ROWS_ 8192
#define GTOT  4194304u

typedef _Float16 half8 __attribute__((ext_vector_type(8)));
typedef _Float16 half4v __attribute__((ext_vector_type(4)));
typedef float f32x4 __attribute__((ext_vector_type(4)));

// ---------------- reductions ----------------
__device__ __forceinline__ float waveSum(float v) {
#pragma unroll
  for (int off = 32; off > 0; off >>= 1) v += __shfl_down(v, off, 64);
  return v;
}
__device__ __forceinline__ float waveMax(float v) {
#pragma unroll
  for (int off = 32; off > 0; off >>= 1) v = fmaxf(v, __shfl_down(v, off, 64));
  return v;
}

// ---------------- threefry2x32, key=(0,42) ----------------
__device__ __forceinline__ uint32_t rotl32(uint32_t x, int r) { return (x << r) | (x >> (32 - r)); }

__device__ __forceinline__ void threefry_0_42(uint32_t& x0, uint32_t& x1) {
  const uint32_t ks0 = 0u, ks1 = 42u, ks2 = 0x1BD11BDAu ^ 42u;
#define TF_R(r) { x0 += x1; x1 = rotl32(x1, r); x1 ^= x0; }
  x0 += ks0; x1 += ks1;
  TF_R(13) TF_R(15) TF_R(26) TF_R(6)   x0 += ks1; x1 += ks2 + 1u;
  TF_R(17) TF_R(29) TF_R(16) TF_R(24)  x0 += ks2; x1 += ks0 + 2u;
  TF_R(13) TF_R(15) TF_R(26) TF_R(6)   x0 += ks0; x1 += ks1 + 3u;
  TF_R(17) TF_R(29) TF_R(16) TF_R(24)  x0 += ks1; x1 += ks2 + 4u;
  TF_R(13) TF_R(15) TF_R(26) TF_R(6)   x0 += ks2; x1 += ks0 + 5u;
#undef TF_R
}

__device__ __forceinline__ float bits_to_gumbel(uint32_t bits) {
  const float TINY = 1.1754943508222875e-38f;
  float u = __uint_as_float((bits >> 9) | 0x3f800000u) - 1.0f;
  u = u + TINY;
  u = fmaxf(TINY, u);
  return -logf(-logf(u));
}

// jax_threefry_partitionable: bits[j] = y0^y1 of threefry_{0,42}(0, j)
__global__ __launch_bounds__(256) void gumbel_kernel(float* __restrict__ g) {
  const unsigned j = blockIdx.x * 256u + threadIdx.x;
  uint32_t x0 = 0u, x1 = j;
  threefry_0_42(x0, x1);
  g[j] = bits_to_gumbel(x0 ^ x1);
}

// ---------------- fp32 -> fp16 conversion ----------------
__global__ __launch_bounds__(256) void f2h_kernel(const float* __restrict__ in,
                                                  _Float16* __restrict__ out, int n4) {
  const int i = blockIdx.x * 256 + threadIdx.x;
  if (i < n4) {
    const float4 v = reinterpret_cast<const float4*>(in)[i];
    half4v h;
    h[0] = (_Float16)v.x; h[1] = (_Float16)v.y; h[2] = (_Float16)v.z; h[3] = (_Float16)v.w;
    reinterpret_cast<half4v*>(out)[i] = h;
  }
}

// ---------------- LayerNorm -> fp16 out ----------------
__global__ __launch_bounds__(256) void ln_kernel(const float* __restrict__ in,
                                                 const float* __restrict__ w,
                                                 const float* __restrict__ b,
                                                 _Float16* __restrict__ out) {
  __shared__ float sh[4];
  const int row = blockIdx.x;
  const int tid = threadIdx.x;
  const float4 v = reinterpret_cast<const float4*>(in + (size_t)row * D_)[tid];
  float s = v.x + v.y + v.z + v.w;
  s = waveSum(s);
  if ((tid & 63) == 0) sh[tid >> 6] = s;
  __syncthreads();
  const float mean = (sh[0] + sh[1] + sh[2] + sh[3]) * (1.0f / D_);
  __syncthreads();
  const float dx = v.x - mean, dy = v.y - mean, dz = v.z - mean, dw = v.w - mean;
  float q = dx * dx + dy * dy + dz * dz + dw * dw;
  q = waveSum(q);
  if ((tid & 63) == 0) sh[tid >> 6] = q;
  __syncthreads();
  const float rstd = rsqrtf((sh[0] + sh[1] + sh[2] + sh[3]) * (1.0f / D_) + 1e-5f);
  const float4 wv = reinterpret_cast<const float4*>(w)[tid];
  const float4 bv = reinterpret_cast<const float4*>(b)[tid];
  half4v o;
  o[0] = (_Float16)(dx * rstd * wv.x + bv.x);
  o[1] = (_Float16)(dy * rstd * wv.y + bv.y);
  o[2] = (_Float16)(dz * rstd * wv.z + bv.z);
  o[3] = (_Float16)(dw * rstd * wv.w + bv.w);
  reinterpret_cast<half4v*>(out + (size_t)row * D_)[tid] = o;
}

// ---------------- fast GELU: A&S 7.1.26 erf approx, max err 1.5e-7 ----------------
__device__ __forceinline__ float fast_gelu(float x) {
  const float z = fabsf(x) * 0.70710678118654752f;
  const float t = 1.0f / (1.0f + 0.3275911f * z);
  const float poly = t * (0.254829592f + t * (-0.284496736f +
                      t * (1.421413741f + t * (-1.453152027f + t * 1.061405429f))));
  float erfz = 1.0f - poly * __expf(-z * z);
  erfz = copysignf(erfz, x);
  return 0.5f * x * (1.0f + erfz);
}

#define GLDS16(g, l)                                                             \
  __builtin_amdgcn_global_load_lds((const __attribute__((address_space(1))) void*)(g), \
                                   (__attribute__((address_space(3))) void*)(l), 16, 0, 0)

// ---------------- 8-phase fp16 MFMA GEMM: 256x256 tile, BK=64, 512 thr / 8 waves ----------------
// Waves 2(M) x 4(N); per-wave 128x64 out = 8x4 16x16 frags. LDS 128KB:
// [parity][kc][frag 0..15][512 halves] for A and B. Stage units of 16KB (2 glds/thread),
// strict FIFO issue; tile-start vmcnt(4)+barrier guarantees whole current tile.
template <bool GELU_EP, bool RES, bool OUT_HALF>
__global__ __launch_bounds__(512) void hgemm8_kernel(const _Float16* __restrict__ A,
                                                     const _Float16* __restrict__ W,
                                                     const float* __restrict__ bias,
                                                     const float* __restrict__ res,
                                                     void* __restrict__ Cout,
                                                     int Nn, int K, int nbx) {
  __shared__ __align__(16) _Float16 Asb[2][2][16 * 512];  // 64KB
  __shared__ __align__(16) _Float16 Bsb[2][2][16 * 512];  // 64KB

  const int tid = threadIdx.x;
  const int lane = tid & 63;
  const int wv = tid >> 6;             // 0..7
  const int wr = wv >> 2, wc = wv & 3;
  const int fr = lane & 15;
  const int k8 = (lane >> 4) << 3;

  // bijective XCD swizzle (grids are multiples of 8)
  const int nwg = (int)gridDim.x;
  const int q8 = nwg >> 3, r8 = nwg & 7;
  const int x = (int)blockIdx.x & 7, idx = (int)blockIdx.x >> 3;
  const int wg = (x < r8 ? x * (q8 + 1) : r8 * (q8 + 1) + (x - r8) * q8) + idx;
  const int m0 = (wg / nbx) * 256, n0 = (wg % nbx) * 256;

  const int KT = K >> 6;   // K-tiles of 64

#define STAGE_A(pt, kc, kt)                                                           \
  { _Pragma("unroll") for (int rho = 0; rho < 2; ++rho) {                             \
      const int f = rho * 8 + wv;                                                     \
      GLDS16(A + (size_t)(m0 + f * 16 + fr) * K + (kt) * 64 + (kc) * 32 + k8,         \
             &Asb[pt][kc][f * 512]); } }
#define STAGE_B(pt, kc, kt)                                                           \
  { _Pragma("unroll") for (int rho = 0; rho < 2; ++rho) {                             \
      const int f = rho * 8 + wv;                                                     \
      GLDS16(W + (size_t)(n0 + f * 16 + fr) * K + (kt) * 64 + (kc) * 32 + k8,         \
             &Bsb[pt][kc][f * 512]); } }

  f32x4 acc[8][4];
#pragma unroll
  for (int i = 0; i < 8; ++i)
#pragma unroll
    for (int j = 0; j < 4; ++j) acc[i][j] = (f32x4)0.0f;

  // prologue: units 0..5 = tile0{Akc0,Bkc0,Akc1,Bkc1}, tile1{Akc0,Bkc0}
  STAGE_A(0, 0, 0); STAGE_B(0, 0, 0);
  STAGE_A(0, 1, 0); STAGE_B(0, 1, 0);
  STAGE_A(1, 0, 1); STAGE_B(1, 0, 1);

  half8 af[4], ag[4], bf[4];
  for (int t = 0; t < KT; ++t) {
    const int p = t & 1;
    // ---- phase 0: A kc0 lo + B kc0 ----
    if (t == KT - 1) { asm volatile("s_waitcnt vmcnt(0)" ::: "memory"); }
    else             { asm volatile("s_waitcnt vmcnt(4)" ::: "memory"); }
    __builtin_amdgcn_s_barrier();
#pragma unroll
    for (int i = 0; i < 4; ++i)
      af[i] = *reinterpret_cast<const half8*>(&Asb[p][0][(wr * 8 + i) * 512 + lane * 8]);
#pragma unroll
    for (int j = 0; j < 4; ++j)
      bf[j] = *reinterpret_cast<const half8*>(&Bsb[p][0][(wc * 4 + j) * 512 + lane * 8]);
    if (t + 1 < KT) STAGE_A(p ^ 1, 1, t + 1);
    __builtin_amdgcn_s_barrier();
    asm volatile("s_waitcnt lgkmcnt(0)" ::: "memory");
    __builtin_amdgcn_s_setprio(1);
#pragma unroll
    for (int i = 0; i < 4; ++i)
#pragma unroll
      for (int j = 0; j < 4; ++j)
        acc[i][j] = __builtin_amdgcn_mfma_f32_16x16x32_f16(af[i], bf[j], acc[i][j], 0, 0, 0);
    __builtin_amdgcn_s_setprio(0);
    __builtin_amdgcn_s_barrier();
    // ---- phase 1: A kc0 hi (reuse bf) ----
#pragma unroll
    for (int i = 0; i < 4; ++i)
      ag[i] = *reinterpret_cast<const half8*>(&Asb[p][0][(wr * 8 + 4 + i) * 512 + lane * 8]);
    if (t + 1 < KT) STAGE_B(p ^ 1, 1, t + 1);
    __builtin_amdgcn_s_barrier();
    asm volatile("s_waitcnt lgkmcnt(0)" ::: "memory");
    __builtin_amdgcn_s_setprio(1);
#pragma unroll
    for (int i = 0; i < 4; ++i)
#pragma unroll
      for (int j = 0; j < 4; ++j)
        acc[4 + i][j] = __builtin_amdgcn_mfma_f32_16x16x32_f16(ag[i], bf[j], acc[4 + i][j], 0, 0, 0);
    __builtin_amdgcn_s_setprio(0);
    __builtin_amdgcn_s_barrier();
    // ---- phase 2: A kc1 lo + B kc1 ----
#pragma unroll
    for (int i = 0; i < 4; ++i)
      af[i] = *reinterpret_cast<const half8*>(&Asb[p][1][(wr * 8 + i) * 512 + lane * 8]);
#pragma unroll
    for (int j = 0; j < 4; ++j)
      bf[j] = *reinterpret_cast<const half8*>(&Bsb[p][1][(wc * 4 + j) * 512 + lane * 8]);
    if (t + 2 < KT) STAGE_A(p, 0, t + 2);
    __builtin_amdgcn_s_barrier();
    asm volatile("s_waitcnt lgkmcnt(0)" ::: "memory");
    __builtin_amdgcn_s_setprio(1);
#pragma unroll
    for (int i = 0; i < 4; ++i)
#pragma unroll
      for (int j = 0; j < 4; ++j)
        acc[i][j] = __builtin_amdgcn_mfma_f32_16x16x32_f16(af[i], bf[j], acc[i][j], 0, 0, 0);
    __builtin_amdgcn_s_setprio(0);
    __builtin_amdgcn_s_barrier();
    // ---- phase 3: A kc1 hi ----
#pragma unroll
    for (int i = 0; i < 4; ++i)
      ag[i] = *reinterpret_cast<const half8*>(&Asb[p][1][(wr * 8 + 4 + i) * 512 + lane * 8]);
    if (t + 2 < KT) STAGE_B(p, 0, t + 2);
    __builtin_amdgcn_s_barrier();
    asm volatile("s_waitcnt lgkmcnt(0)" ::: "memory");
    __builtin_amdgcn_s_setprio(1);
#pragma unroll
    for (int i = 0; i < 4; ++i)
#pragma unroll
      for (int j = 0; j < 4; ++j)
        acc[4 + i][j] = __builtin_amdgcn_mfma_f32_16x16x32_f16(ag[i], bf[j], acc[4 + i][j], 0, 0, 0);
    __builtin_amdgcn_s_setprio(0);
    __builtin_amdgcn_s_barrier();
  }
#undef STAGE_A
#undef STAGE_B

  // epilogue: C/D layout col=lane&15, row=(lane>>4)*4+reg
  float bv[4];
#pragma unroll
  for (int nf = 0; nf < 4; ++nf) bv[nf] = bias[n0 + wc * 64 + nf * 16 + fr];
#pragma unroll
  for (int mf = 0; mf < 8; ++mf) {
#pragma unroll
    for (int r = 0; r < 4; ++r) {
      const int row = m0 + wr * 128 + mf * 16 + ((lane >> 4) << 2) + r;
      const size_t ro = (size_t)row * Nn;
#pragma unroll
      for (int nf = 0; nf < 4; ++nf) {
        const int col = n0 + wc * 64 + nf * 16 + fr;
        float u = acc[mf][nf][r] + bv[nf];
        if (GELU_EP) u = fast_gelu(u);
        if (RES) u += res[ro + col];
        if (OUT_HALF) ((_Float16*)Cout)[ro + col] = (_Float16)u;
        else          ((float*)Cout)[ro + col] = u;
      }
    }
  }
}

// ---------------- MFMA flash attention (fp16 in/out, fp32 softmax/acc) ----------------
__global__ __launch_bounds__(256) void mattn_kernel(const _Float16* __restrict__ qkv,
                                                    _Float16* __restrict__ ctx) {
  __shared__ __align__(16) _Float16 Ks[64][72];
  __shared__ __align__(16) _Float16 Vt[64][72];
  __shared__ __align__(16) _Float16 Ps[4][16][72];
  const int qt = blockIdx.x, h = blockIdx.y, b = blockIdx.z;
  const int tid = threadIdx.x;
  const int lane = tid & 63;
  const int w = tid >> 6;
  const int l15 = lane & 15;
  const int koff = (lane >> 4) * 8;

  const size_t qrow = (size_t)b * N_ + qt * 64 + w * 16 + l15;
  // fold 1/sqrt(64) into Q (exact: exponent-only scale)
  half8 qf0 = *reinterpret_cast<const half8*>(qkv + qrow * 3072 + h * 64 + koff);
  half8 qf1 = *reinterpret_cast<const half8*>(qkv + qrow * 3072 + h * 64 + 32 + koff);
  qf0 *= (_Float16)0.125f;
  qf1 *= (_Float16)0.125f;

  const int skey = tid >> 2;
  const int sch = (tid & 3) * 16;

  float m_i[4], l_i[4];
  f32x4 oacc[4];
#pragma unroll
  for (int r = 0; r < 4; ++r) { m_i[r] = -3.0e38f; l_i[r] = 0.0f; }
#pragma unroll
  for (int jb = 0; jb < 4; ++jb) oacc[jb] = (f32x4)0.0f;

  for (int kt = 0; kt < 16; ++kt) {
    __syncthreads();
    const _Float16* krow = qkv + ((size_t)b * N_ + kt * 64 + skey) * 3072 + 1024 + h * 64 + sch;
    half8 k0 = *reinterpret_cast<const half8*>(krow);
    half8 k1 = *reinterpret_cast<const half8*>(krow + 8);
    half8 v0 = *reinterpret_cast<const half8*>(krow + 1024);
    half8 v1 = *reinterpret_cast<const half8*>(krow + 1032);
    *reinterpret_cast<half8*>(&Ks[skey][sch]) = k0;
    *reinterpret_cast<half8*>(&Ks[skey][sch + 8]) = k1;
#pragma unroll
    for (int j = 0; j < 8; ++j) {
      Vt[sch + j][skey] = v0[j];
      Vt[sch + 8 + j][skey] = v1[j];
    }
    __syncthreads();

    f32x4 sacc[4];
#pragma unroll
    for (int jb = 0; jb < 4; ++jb) sacc[jb] = (f32x4)0.0f;
#pragma unroll
    for (int jb = 0; jb < 4; ++jb) {
      half8 kfa = *reinterpret_cast<const half8*>(&Ks[jb * 16 + l15][koff]);
      half8 kfb = *reinterpret_cast<const half8*>(&Ks[jb * 16 + l15][32 + koff]);
      sacc[jb] = __builtin_amdgcn_mfma_f32_16x16x32_f16(qf0, kfa, sacc[jb], 0, 0, 0);
      sacc[jb] = __builtin_amdgcn_mfma_f32_16x16x32_f16(qf1, kfb, sacc[jb], 0, 0, 0);
    }

    float p[4][4];
#pragma unroll
    for (int r = 0; r < 4; ++r) {
      float mx = fmaxf(fmaxf(sacc[0][r], sacc[1][r]), fmaxf(sacc[2][r], sacc[3][r]));
#pragma unroll
      for (int mk = 1; mk < 16; mk <<= 1) mx = fmaxf(mx, __shfl_xor(mx, mk, 64));
      const float nm = fmaxf(m_i[r], mx);
      const float scale = __expf(m_i[r] - nm);
      float rs = 0.0f;
#pragma unroll
      for (int jb = 0; jb < 4; ++jb) { p[jb][r] = __expf(sacc[jb][r] - nm); rs += p[jb][r]; }
#pragma unroll
      for (int mk = 1; mk < 16; mk <<= 1) rs += __shfl_xor(rs, mk, 64);
      l_i[r] = l_i[r] * scale + rs;
      m_i[r] = nm;
#pragma unroll
      for (int jb = 0; jb < 4; ++jb) oacc[jb][r] *= scale;
    }

#pragma unroll
    for (int jb = 0; jb < 4; ++jb)
#pragma unroll
      for (int r = 0; r < 4; ++r)
        Ps[w][(lane >> 4) * 4 + r][jb * 16 + l15] = (_Float16)p[jb][r];

    half8 pf0 = *reinterpret_cast<const half8*>(&Ps[w][l15][koff]);
    half8 pf1 = *reinterpret_cast<const half8*>(&Ps[w][l15][32 + koff]);
#pragma unroll
    for (int jb = 0; jb < 4; ++jb) {
      half8 vf0 = *reinterpret_cast<const half8*>(&Vt[jb * 16 + l15][koff]);
      half8 vf1 = *reinterpret_cast<const half8*>(&Vt[jb * 16 + l15][32 + koff]);
      oacc[jb] = __builtin_amdgcn_mfma_f32_16x16x32_f16(pf0, vf0, oacc[jb], 0, 0, 0);
      oacc[jb] = __builtin_amdgcn_mfma_f32_16x16x32_f16(pf1, vf1, oacc[jb], 0, 0, 0);
    }
  }

#pragma unroll
  for (int jb = 0; jb < 4; ++jb)
#pragma unroll
    for (int r = 0; r < 4; ++r) {
      const size_t orow = (size_t)b * N_ + qt * 64 + w * 16 + (lane >> 4) * 4 + r;
      ctx[orow * 1024 + h * 64 + jb * 16 + l15] = (_Float16)(oacc[jb][r] / l_i[r]);
    }
}

// ---------------- score ----------------
__global__ __launch_bounds__(256) void score_kernel(const float* __restrict__ hbuf,
                                                    const float* __restrict__ lw,
                                                    float* __restrict__ mp) {
  __shared__ float sh[4];
  const int row = blockIdx.x, tid = threadIdx.x;
  const float4 v = reinterpret_cast<const float4*>(hbuf + (size_t)row * D_)[tid];
  const float4 w = reinterpret_cast<const float4*>(lw)[tid];
  float s = v.x * w.x + v.y * w.y + v.z * w.z + v.w * w.w;
  s = waveSum(s);
  if ((tid & 63) == 0) sh[tid >> 6] = s;
  __syncthreads();
  if (tid == 0) mp[row] = sh[0] + sh[1] + sh[2] + sh[3];
}

// ---------------- lse over n of 2*(mp+g) ----------------
__global__ __launch_bounds__(256) void lse_kernel(const float* __restrict__ g,
                                                  const float* __restrict__ mp,
                                                  float* __restrict__ lse) {
  __shared__ float sh[4];
  const int row = blockIdx.x;          // k*8+b
  const int b = row & 7;
  const int tid = threadIdx.x;
  const float4 gv = reinterpret_cast<const float4*>(g + (size_t)row * 1024)[tid];
  const float4 mv = reinterpret_cast<const float4*>(mp + b * 1024)[tid];
  const float l0 = 2.0f * (gv.x + mv.x), l1 = 2.0f * (gv.y + mv.y);
  const float l2 = 2.0f * (gv.z + mv.z), l3 = 2.0f * (gv.w + mv.w);
  float mx = fmaxf(fmaxf(l0, l1), fmaxf(l2, l3));
  mx = waveMax(mx);
  if ((tid & 63) == 0) sh[tid >> 6] = mx;
  __syncthreads();
  mx = fmaxf(fmaxf(sh[0], sh[1]), fmaxf(sh[2], sh[3]));
  __syncthreads();
  float se = expf(l0 - mx) + expf(l1 - mx) + expf(l2 - mx) + expf(l3 - mx);
  se = waveSum(se);
  if ((tid & 63) == 0) sh[tid >> 6] = se;
  __syncthreads();
  if (tid == 0) lse[row] = mx + logf(sh[0] + sh[1] + sh[2] + sh[3]);
}

// ---------------- z ----------------
__global__ __launch_bounds__(256) void z_kernel(const float* __restrict__ g,
                                                const float* __restrict__ mp,
                                                const float* __restrict__ lse,
                                                float* __restrict__ z) {
  const int idx = blockIdx.x * 256 + threadIdx.x;
  const int b = idx >> 10;
  float best = -3.0e38f;
#pragma unroll 8
  for (int k = 0; k < KD_; ++k) {
    const float gv = g[(size_t)k * ROWS_ + idx];
    best = fmaxf(best, 2.0f * gv - lse[k * 8 + b]);
  }
  z[idx] = expf(2.0f * mp[idx] + best);
}

extern "C" void kernel_launch(void* const* d_in, const int* in_sizes, int n_in,
                              void* d_out, int out_size, void* d_ws, size_t ws_size,
                              hipStream_t stream) {
  (void)in_sizes; (void)n_in; (void)out_size; (void)ws_size;
  const float* f      = (const float*)d_in[0];
  const float* qkv_w  = (const float*)d_in[2];
  const float* qkv_b  = (const float*)d_in[3];
  const float* proj_w = (const float*)d_in[4];
  const float* proj_b = (const float*)d_in[5];
  const float* ln1_w  = (const float*)d_in[6];
  const float* ln1_b  = (const float*)d_in[7];
  const float* ln2_w  = (const float*)d_in[8];
  const float* ln2_b  = (const float*)d_in[9];
  const float* fc1_w  = (const float*)d_in[10];
  const float* fc1_b  = (const float*)d_in[11];
  const float* fc2_w  = (const float*)d_in[12];
  const float* fc2_b  = (const float*)d_in[13];
  const float* lin_w  = (const float*)d_in[14];
  float* out = (float*)d_out;

  // -------- workspace (f32 offsets; peak 44,052,480 f32 = 176 MB) --------
  float* ws = (float*)d_ws;
  _Float16* wh = (_Float16*)d_ws;
  _Float16* QKVWH  = wh;                        // 3,145,728 h
  _Float16* PROJWH = wh + 3145728;              // 1,048,576 h
  _Float16* FC1WH  = wh + 4194304;              // 4,194,304 h
  _Float16* FC2WH  = wh + 8388608;              // 4,194,304 h -> ends f32 6,291,456
  float* MP  = ws + 6291456;                    // 8192
  float* LSE = ws + 6299648;                    // 4096
  _Float16* XH   = (_Float16*)(ws + 6303744);   // 8,388,608 h
  _Float16* QKVH = (_Float16*)(ws + 10498048);  // 25,165,824 h (dead after attn)
  _Float16* CTXH = (_Float16*)(ws + 23080960);  // 8,388,608 h
  _Float16* YH   = (_Float16*)(ws + 10498048);  // 16,777,216 h (reuses QKVH)
  float* F1   = ws + 27275264;                  // 8,388,608 f32
  float* Hbuf = ws + 35663872;                  // 8,388,608 f32 -> end 44,052,480
  float* G    = ws;                             // 4,194,304 f32 (weights dead by then)

  f2h_kernel<<<3072, 256, 0, stream>>>(qkv_w, QKVWH, 786432);
  f2h_kernel<<<1024, 256, 0, stream>>>(proj_w, PROJWH, 262144);
  f2h_kernel<<<4096, 256, 0, stream>>>(fc1_w, FC1WH, 1048576);
  f2h_kernel<<<4096, 256, 0, stream>>>(fc2_w, FC2WH, 1048576);

  ln_kernel<<<ROWS_, 256, 0, stream>>>(f, ln1_w, ln1_b, XH);
  // qkv: M=8192 N=3072 K=1024 -> 32x12 = 384 blocks
  hgemm8_kernel<false, false, true><<<384, 512, 0, stream>>>(XH, QKVWH, qkv_b, nullptr, QKVH, 3072, 1024, 12);
  mattn_kernel<<<dim3(16, 16, 8), 256, 0, stream>>>(QKVH, CTXH);
  // proj: M=8192 N=1024 K=1024 -> 32x4 = 128 blocks
  hgemm8_kernel<false, true, false><<<128, 512, 0, stream>>>(CTXH, PROJWH, proj_b, f, F1, 1024, 1024, 4);
  ln_kernel<<<ROWS_, 256, 0, stream>>>(F1, ln2_w, ln2_b, XH);
  // fc1: M=8192 N=4096 K=1024 -> 32x16 = 512 blocks
  hgemm8_kernel<true, false, true><<<512, 512, 0, stream>>>(XH, FC1WH, fc1_b, nullptr, YH, 4096, 1024, 16);
  // fc2: M=8192 N=1024 K=4096 -> 32x4 = 128 blocks
  hgemm8_kernel<false, true, false><<<128, 512, 0, stream>>>(YH, FC2WH, fc2_b, F1, Hbuf, 1024, 4096, 4);
  score_kernel<<<ROWS_, 256, 0, stream>>>(Hbuf, lin_w, MP);
  gumbel_kernel<<<GTOT / 256, 256, 0, stream>>>(G);
  lse_kernel<<<KD_ * B_, 256, 0, stream>>>(G, MP, LSE);
  z_kernel<<<ROWS_ / 256, 256, 0, stream>>>(G, MP, LSE, out);
}

// Round 8
// 533.896 us; speedup vs baseline: 1.5134x; 1.2104x over previous
//
#include <hip/hip_runtime.h>
#include <hip/hip_bf16.h>
#include <math.h>

#define B_    8
#define N_    1024
#define D_    1024
#define H_    16
#define DH_   64
#define HID_  4096
#define KD_   512
#define ROWS_ 8192
#define GTOT  4194304u

typedef _Float16 half8 __attribute__((ext_vector_type(8)));
typedef _Float16 half4v __attribute__((ext_vector_type(4)));
typedef float f32x4 __attribute__((ext_vector_type(4)));

// ---------------- reductions ----------------
__device__ __forceinline__ float waveSum(float v) {
#pragma unroll
  for (int off = 32; off > 0; off >>= 1) v += __shfl_down(v, off, 64);
  return v;
}
__device__ __forceinline__ float waveMax(float v) {
#pragma unroll
  for (int off = 32; off > 0; off >>= 1) v = fmaxf(v, __shfl_down(v, off, 64));
  return v;
}

// ---------------- threefry2x32, key=(0,42) ----------------
__device__ __forceinline__ uint32_t rotl32(uint32_t x, int r) { return (x << r) | (x >> (32 - r)); }

__device__ __forceinline__ void threefry_0_42(uint32_t& x0, uint32_t& x1) {
  const uint32_t ks0 = 0u, ks1 = 42u, ks2 = 0x1BD11BDAu ^ 42u;
#define TF_R(r) { x0 += x1; x1 = rotl32(x1, r); x1 ^= x0; }
  x0 += ks0; x1 += ks1;
  TF_R(13) TF_R(15) TF_R(26) TF_R(6)   x0 += ks1; x1 += ks2 + 1u;
  TF_R(17) TF_R(29) TF_R(16) TF_R(24)  x0 += ks2; x1 += ks0 + 2u;
  TF_R(13) TF_R(15) TF_R(26) TF_R(6)   x0 += ks0; x1 += ks1 + 3u;
  TF_R(17) TF_R(29) TF_R(16) TF_R(24)  x0 += ks1; x1 += ks2 + 4u;
  TF_R(13) TF_R(15) TF_R(26) TF_R(6)   x0 += ks2; x1 += ks0 + 5u;
#undef TF_R
}

__device__ __forceinline__ float bits_to_gumbel(uint32_t bits) {
  const float TINY = 1.1754943508222875e-38f;
  float u = __uint_as_float((bits >> 9) | 0x3f800000u) - 1.0f;
  u = u + TINY;
  u = fmaxf(TINY, u);
  return -logf(-logf(u));
}

// jax_threefry_partitionable: bits[j] = y0^y1 of threefry_{0,42}(0, j)
__global__ __launch_bounds__(256) void gumbel_kernel(float* __restrict__ g) {
  const unsigned j = blockIdx.x * 256u + threadIdx.x;
  uint32_t x0 = 0u, x1 = j;
  threefry_0_42(x0, x1);
  g[j] = bits_to_gumbel(x0 ^ x1);
}

// ---------------- fp32 -> fp16 conversion ----------------
__global__ __launch_bounds__(256) void f2h_kernel(const float* __restrict__ in,
                                                  _Float16* __restrict__ out, int n4) {
  const int i = blockIdx.x * 256 + threadIdx.x;
  if (i < n4) {
    const float4 v = reinterpret_cast<const float4*>(in)[i];
    half4v h;
    h[0] = (_Float16)v.x; h[1] = (_Float16)v.y; h[2] = (_Float16)v.z; h[3] = (_Float16)v.w;
    reinterpret_cast<half4v*>(out)[i] = h;
  }
}

// ---------------- LayerNorm -> fp16 out ----------------
__global__ __launch_bounds__(256) void ln_kernel(const float* __restrict__ in,
                                                 const float* __restrict__ w,
                                                 const float* __restrict__ b,
                                                 _Float16* __restrict__ out) {
  __shared__ float sh[4];
  const int row = blockIdx.x;
  const int tid = threadIdx.x;
  const float4 v = reinterpret_cast<const float4*>(in + (size_t)row * D_)[tid];
  float s = v.x + v.y + v.z + v.w;
  s = waveSum(s);
  if ((tid & 63) == 0) sh[tid >> 6] = s;
  __syncthreads();
  const float mean = (sh[0] + sh[1] + sh[2] + sh[3]) * (1.0f / D_);
  __syncthreads();
  const float dx = v.x - mean, dy = v.y - mean, dz = v.z - mean, dw = v.w - mean;
  float q = dx * dx + dy * dy + dz * dz + dw * dw;
  q = waveSum(q);
  if ((tid & 63) == 0) sh[tid >> 6] = q;
  __syncthreads();
  const float rstd = rsqrtf((sh[0] + sh[1] + sh[2] + sh[3]) * (1.0f / D_) + 1e-5f);
  const float4 wv = reinterpret_cast<const float4*>(w)[tid];
  const float4 bv = reinterpret_cast<const float4*>(b)[tid];
  half4v o;
  o[0] = (_Float16)(dx * rstd * wv.x + bv.x);
  o[1] = (_Float16)(dy * rstd * wv.y + bv.y);
  o[2] = (_Float16)(dz * rstd * wv.z + bv.z);
  o[3] = (_Float16)(dw * rstd * wv.w + bv.w);
  reinterpret_cast<half4v*>(out + (size_t)row * D_)[tid] = o;
}

// ---------------- fast GELU: A&S 7.1.26 erf approx, max err 1.5e-7 ----------------
__device__ __forceinline__ float fast_gelu(float x) {
  const float z = fabsf(x) * 0.70710678118654752f;
  const float t = 1.0f / (1.0f + 0.3275911f * z);
  const float poly = t * (0.254829592f + t * (-0.284496736f +
                      t * (1.421413741f + t * (-1.453152027f + t * 1.061405429f))));
  float erfz = 1.0f - poly * __expf(-z * z);
  erfz = copysignf(erfz, x);
  return 0.5f * x * (1.0f + erfz);
}

#define GLDS16(g, l)                                                             \
  __builtin_amdgcn_global_load_lds((const __attribute__((address_space(1))) void*)(g), \
                                   (__attribute__((address_space(3))) void*)(l), 16, 0, 0)

// ============ A) 4-phase 8-wave 256x256 (qkv — control arm of the A/B) ============
template <bool GELU_EP, bool RES, bool OUT_HALF>
__global__ __launch_bounds__(512) void hgemm8_kernel(const _Float16* __restrict__ A,
                                                     const _Float16* __restrict__ W,
                                                     const float* __restrict__ bias,
                                                     const float* __restrict__ res,
                                                     void* __restrict__ Cout,
                                                     int Nn, int K, int nbx) {
  __shared__ __align__(16) _Float16 Asb[2][2][16 * 512];
  __shared__ __align__(16) _Float16 Bsb[2][2][16 * 512];

  const int tid = threadIdx.x;
  const int lane = tid & 63;
  const int wv = tid >> 6;
  const int wr = wv >> 2, wc = wv & 3;
  const int fr = lane & 15;
  const int k8 = (lane >> 4) << 3;

  const int nwg = (int)gridDim.x;
  const int q8 = nwg >> 3, r8 = nwg & 7;
  const int x = (int)blockIdx.x & 7, idx = (int)blockIdx.x >> 3;
  const int wg = (x < r8 ? x * (q8 + 1) : r8 * (q8 + 1) + (x - r8) * q8) + idx;
  const int m0 = (wg / nbx) * 256, n0 = (wg % nbx) * 256;

  const int KT = K >> 6;

#define STAGE_A(pt, kc, kt)                                                           \
  { _Pragma("unroll") for (int rho = 0; rho < 2; ++rho) {                             \
      const int f = rho * 8 + wv;                                                     \
      GLDS16(A + (size_t)(m0 + f * 16 + fr) * K + (kt) * 64 + (kc) * 32 + k8,         \
             &Asb[pt][kc][f * 512]); } }
#define STAGE_B(pt, kc, kt)                                                           \
  { _Pragma("unroll") for (int rho = 0; rho < 2; ++rho) {                             \
      const int f = rho * 8 + wv;                                                     \
      GLDS16(W + (size_t)(n0 + f * 16 + fr) * K + (kt) * 64 + (kc) * 32 + k8,         \
             &Bsb[pt][kc][f * 512]); } }

  f32x4 acc[8][4];
#pragma unroll
  for (int i = 0; i < 8; ++i)
#pragma unroll
    for (int j = 0; j < 4; ++j) acc[i][j] = (f32x4)0.0f;

  STAGE_A(0, 0, 0); STAGE_B(0, 0, 0);
  STAGE_A(0, 1, 0); STAGE_B(0, 1, 0);
  STAGE_A(1, 0, 1); STAGE_B(1, 0, 1);

  half8 af[4], ag[4], bf[4];
  for (int t = 0; t < KT; ++t) {
    const int p = t & 1;
    if (t == KT - 1) { asm volatile("s_waitcnt vmcnt(0)" ::: "memory"); }
    else             { asm volatile("s_waitcnt vmcnt(4)" ::: "memory"); }
    __builtin_amdgcn_s_barrier();
#pragma unroll
    for (int i = 0; i < 4; ++i)
      af[i] = *reinterpret_cast<const half8*>(&Asb[p][0][(wr * 8 + i) * 512 + lane * 8]);
#pragma unroll
    for (int j = 0; j < 4; ++j)
      bf[j] = *reinterpret_cast<const half8*>(&Bsb[p][0][(wc * 4 + j) * 512 + lane * 8]);
    if (t + 1 < KT) STAGE_A(p ^ 1, 1, t + 1);
    __builtin_amdgcn_s_barrier();
    asm volatile("s_waitcnt lgkmcnt(0)" ::: "memory");
    __builtin_amdgcn_s_setprio(1);
#pragma unroll
    for (int i = 0; i < 4; ++i)
#pragma unroll
      for (int j = 0; j < 4; ++j)
        acc[i][j] = __builtin_amdgcn_mfma_f32_16x16x32_f16(af[i], bf[j], acc[i][j], 0, 0, 0);
    __builtin_amdgcn_s_setprio(0);
    __builtin_amdgcn_s_barrier();
#pragma unroll
    for (int i = 0; i < 4; ++i)
      ag[i] = *reinterpret_cast<const half8*>(&Asb[p][0][(wr * 8 + 4 + i) * 512 + lane * 8]);
    if (t + 1 < KT) STAGE_B(p ^ 1, 1, t + 1);
    __builtin_amdgcn_s_barrier();
    asm volatile("s_waitcnt lgkmcnt(0)" ::: "memory");
    __builtin_amdgcn_s_setprio(1);
#pragma unroll
    for (int i = 0; i < 4; ++i)
#pragma unroll
      for (int j = 0; j < 4; ++j)
        acc[4 + i][j] = __builtin_amdgcn_mfma_f32_16x16x32_f16(ag[i], bf[j], acc[4 + i][j], 0, 0, 0);
    __builtin_amdgcn_s_setprio(0);
    __builtin_amdgcn_s_barrier();
#pragma unroll
    for (int i = 0; i < 4; ++i)
      af[i] = *reinterpret_cast<const half8*>(&Asb[p][1][(wr * 8 + i) * 512 + lane * 8]);
#pragma unroll
    for (int j = 0; j < 4; ++j)
      bf[j] = *reinterpret_cast<const half8*>(&Bsb[p][1][(wc * 4 + j) * 512 + lane * 8]);
    if (t + 2 < KT) STAGE_A(p, 0, t + 2);
    __builtin_amdgcn_s_barrier();
    asm volatile("s_waitcnt lgkmcnt(0)" ::: "memory");
    __builtin_amdgcn_s_setprio(1);
#pragma unroll
    for (int i = 0; i < 4; ++i)
#pragma unroll
      for (int j = 0; j < 4; ++j)
        acc[i][j] = __builtin_amdgcn_mfma_f32_16x16x32_f16(af[i], bf[j], acc[i][j], 0, 0, 0);
    __builtin_amdgcn_s_setprio(0);
    __builtin_amdgcn_s_barrier();
#pragma unroll
    for (int i = 0; i < 4; ++i)
      ag[i] = *reinterpret_cast<const half8*>(&Asb[p][1][(wr * 8 + 4 + i) * 512 + lane * 8]);
    if (t + 2 < KT) STAGE_B(p, 0, t + 2);
    __builtin_amdgcn_s_barrier();
    asm volatile("s_waitcnt lgkmcnt(0)" ::: "memory");
    __builtin_amdgcn_s_setprio(1);
#pragma unroll
    for (int i = 0; i < 4; ++i)
#pragma unroll
      for (int j = 0; j < 4; ++j)
        acc[4 + i][j] = __builtin_amdgcn_mfma_f32_16x16x32_f16(ag[i], bf[j], acc[4 + i][j], 0, 0, 0);
    __builtin_amdgcn_s_setprio(0);
    __builtin_amdgcn_s_barrier();
  }
#undef STAGE_A
#undef STAGE_B

  float bv[4];
#pragma unroll
  for (int nf = 0; nf < 4; ++nf) bv[nf] = bias[n0 + wc * 64 + nf * 16 + fr];
#pragma unroll
  for (int mf = 0; mf < 8; ++mf) {
#pragma unroll
    for (int r = 0; r < 4; ++r) {
      const int row = m0 + wr * 128 + mf * 16 + ((lane >> 4) << 2) + r;
      const size_t ro = (size_t)row * Nn;
#pragma unroll
      for (int nf = 0; nf < 4; ++nf) {
        const int col = n0 + wc * 64 + nf * 16 + fr;
        float u = acc[mf][nf][r] + bv[nf];
        if (GELU_EP) u = fast_gelu(u);
        if (RES) u += res[ro + col];
        if (OUT_HALF) ((_Float16*)Cout)[ro + col] = (_Float16)u;
        else          ((float*)Cout)[ro + col] = u;
      }
    }
  }
}

// ============ B) 2-phase-wide 8-wave 256x256 (fc1 — experiment arm) ============
template <bool GELU_EP, bool RES, bool OUT_HALF>
__global__ __launch_bounds__(512) void hgemm8w_kernel(const _Float16* __restrict__ A,
                                                      const _Float16* __restrict__ W,
                                                      const float* __restrict__ bias,
                                                      const float* __restrict__ res,
                                                      void* __restrict__ Cout,
                                                      int Nn, int K, int nbx) {
  __shared__ __align__(16) _Float16 Asb[2][2][16 * 512];
  __shared__ __align__(16) _Float16 Bsb[2][2][16 * 512];

  const int tid = threadIdx.x;
  const int lane = tid & 63;
  const int wv = tid >> 6;
  const int wr = wv >> 2, wc = wv & 3;
  const int fr = lane & 15;
  const int k8 = (lane >> 4) << 3;

  const int nwg = (int)gridDim.x;
  const int q8 = nwg >> 3, r8 = nwg & 7;
  const int x = (int)blockIdx.x & 7, idx = (int)blockIdx.x >> 3;
  const int wg = (x < r8 ? x * (q8 + 1) : r8 * (q8 + 1) + (x - r8) * q8) + idx;
  const int m0 = (wg / nbx) * 256, n0 = (wg % nbx) * 256;

  const int KT = K >> 6;

#define STAGE_A(pt, kc, kt)                                                           \
  { _Pragma("unroll") for (int rho = 0; rho < 2; ++rho) {                             \
      const int f = rho * 8 + wv;                                                     \
      GLDS16(A + (size_t)(m0 + f * 16 + fr) * K + (kt) * 64 + (kc) * 32 + k8,         \
             &Asb[pt][kc][f * 512]); } }
#define STAGE_B(pt, kc, kt)                                                           \
  { _Pragma("unroll") for (int rho = 0; rho < 2; ++rho) {                             \
      const int f = rho * 8 + wv;                                                     \
      GLDS16(W + (size_t)(n0 + f * 16 + fr) * K + (kt) * 64 + (kc) * 32 + k8,         \
             &Bsb[pt][kc][f * 512]); } }

  f32x4 acc[8][4];
#pragma unroll
  for (int i = 0; i < 8; ++i)
#pragma unroll
    for (int j = 0; j < 4; ++j) acc[i][j] = (f32x4)0.0f;

  // prologue FIFO: kc0(0)+kc1(0)+kc0(1) = 12 glds
  STAGE_A(0, 0, 0); STAGE_B(0, 0, 0);
  STAGE_A(0, 1, 0); STAGE_B(0, 1, 0);
  STAGE_A(1, 0, 1); STAGE_B(1, 0, 1);

  half8 af[4], ag[4], bf[4];
  for (int t = 0; t < KT; ++t) {
    const int p = t & 1;
    // oldest-first: everything except the newest 4 (kc0(t+1)) completes
    if (t == KT - 1) { asm volatile("s_waitcnt vmcnt(0)" ::: "memory"); }
    else             { asm volatile("s_waitcnt vmcnt(4)" ::: "memory"); }
    __builtin_amdgcn_s_barrier();
#pragma unroll
    for (int kc = 0; kc < 2; ++kc) {
#pragma unroll
      for (int i = 0; i < 4; ++i)
        af[i] = *reinterpret_cast<const half8*>(&Asb[p][kc][(wr * 8 + i) * 512 + lane * 8]);
#pragma unroll
      for (int i = 0; i < 4; ++i)
        ag[i] = *reinterpret_cast<const half8*>(&Asb[p][kc][(wr * 8 + 4 + i) * 512 + lane * 8]);
#pragma unroll
      for (int j = 0; j < 4; ++j)
        bf[j] = *reinterpret_cast<const half8*>(&Bsb[p][kc][(wc * 4 + j) * 512 + lane * 8]);
      if (kc == 0) { if (t + 1 < KT) { STAGE_A(p ^ 1, 1, t + 1); STAGE_B(p ^ 1, 1, t + 1); } }
      else         { if (t + 2 < KT) { STAGE_A(p, 0, t + 2);     STAGE_B(p, 0, t + 2); } }
      __builtin_amdgcn_s_barrier();
      asm volatile("s_waitcnt lgkmcnt(0)" ::: "memory");
      __builtin_amdgcn_s_setprio(1);
#pragma unroll
      for (int i = 0; i < 4; ++i)
#pragma unroll
        for (int j = 0; j < 4; ++j)
          acc[i][j] = __builtin_amdgcn_mfma_f32_16x16x32_f16(af[i], bf[j], acc[i][j], 0, 0, 0);
#pragma unroll
      for (int i = 0; i < 4; ++i)
#pragma unroll
        for (int j = 0; j < 4; ++j)
          acc[4 + i][j] = __builtin_amdgcn_mfma_f32_16x16x32_f16(ag[i], bf[j], acc[4 + i][j], 0, 0, 0);
      __builtin_amdgcn_s_setprio(0);
      __builtin_amdgcn_s_barrier();
    }
  }
#undef STAGE_A
#undef STAGE_B

  float bv[4];
#pragma unroll
  for (int nf = 0; nf < 4; ++nf) bv[nf] = bias[n0 + wc * 64 + nf * 16 + fr];
#pragma unroll
  for (int mf = 0; mf < 8; ++mf) {
#pragma unroll
    for (int r = 0; r < 4; ++r) {
      const int row = m0 + wr * 128 + mf * 16 + ((lane >> 4) << 2) + r;
      const size_t ro = (size_t)row * Nn;
#pragma unroll
      for (int nf = 0; nf < 4; ++nf) {
        const int col = n0 + wc * 64 + nf * 16 + fr;
        float u = acc[mf][nf][r] + bv[nf];
        if (GELU_EP) u = fast_gelu(u);
        if (RES) u += res[ro + col];
        if (OUT_HALF) ((_Float16*)Cout)[ro + col] = (_Float16)u;
        else          ((float*)Cout)[ro + col] = u;
      }
    }
  }
}

// ============ C) 128x256 8-wave, 1-ahead (proj & fc2 — full-machine grids) ============
template <bool GELU_EP, bool RES, bool OUT_HALF>
__global__ __launch_bounds__(512) void hgemm128_kernel(const _Float16* __restrict__ A,
                                                       const _Float16* __restrict__ W,
                                                       const float* __restrict__ bias,
                                                       const float* __restrict__ res,
                                                       void* __restrict__ Cout,
                                                       int Nn, int K, int nbx) {
  __shared__ __align__(16) _Float16 Ab[2][2][8 * 512];    // 32KB
  __shared__ __align__(16) _Float16 Bb[2][2][16 * 512];   // 64KB

  const int tid = threadIdx.x;
  const int lane = tid & 63;
  const int wv = tid >> 6;
  const int wr = wv >> 2, wc = wv & 3;       // wave = 64x64 out tile
  const int fr = lane & 15;
  const int k8 = (lane >> 4) << 3;

  const int nwg = (int)gridDim.x;
  const int q8 = nwg >> 3, r8 = nwg & 7;
  const int x = (int)blockIdx.x & 7, idx = (int)blockIdx.x >> 3;
  const int wg = (x < r8 ? x * (q8 + 1) : r8 * (q8 + 1) + (x - r8) * q8) + idx;
  const int m0 = (wg / nbx) * 128, n0 = (wg % nbx) * 256;

  const int KT = K >> 6;

#define STAGE_A1(pt, kt)                                                              \
  { _Pragma("unroll") for (int kc = 0; kc < 2; ++kc)                                  \
      GLDS16(A + (size_t)(m0 + wv * 16 + fr) * K + (kt) * 64 + kc * 32 + k8,          \
             &Ab[pt][kc][wv * 512]); }
#define STAGE_B1(pt, kt)                                                              \
  { _Pragma("unroll") for (int u = 0; u < 2; ++u)                                     \
      _Pragma("unroll") for (int kc = 0; kc < 2; ++kc)                                \
        GLDS16(W + (size_t)(n0 + (u * 8 + wv) * 16 + fr) * K + (kt) * 64 + kc * 32 + k8, \
               &Bb[pt][kc][(u * 8 + wv) * 512]); }

  f32x4 acc[4][4];
#pragma unroll
  for (int i = 0; i < 4; ++i)
#pragma unroll
    for (int j = 0; j < 4; ++j) acc[i][j] = (f32x4)0.0f;

  STAGE_A1(0, 0); STAGE_B1(0, 0);

  half8 af[4], bf[4];
  for (int t = 0; t < KT; ++t) {
    const int p = t & 1;
    asm volatile("s_waitcnt vmcnt(0)" ::: "memory");
    __builtin_amdgcn_s_barrier();
#pragma unroll
    for (int kc = 0; kc < 2; ++kc) {
#pragma unroll
      for (int i = 0; i < 4; ++i)
        af[i] = *reinterpret_cast<const half8*>(&Ab[p][kc][(wr * 4 + i) * 512 + lane * 8]);
#pragma unroll
      for (int j = 0; j < 4; ++j)
        bf[j] = *reinterpret_cast<const half8*>(&Bb[p][kc][(wc * 4 + j) * 512 + lane * 8]);
      if (t + 1 < KT) {
        if (kc == 0) STAGE_A1(p ^ 1, t + 1)
        else         STAGE_B1(p ^ 1, t + 1)
      }
      __builtin_amdgcn_s_barrier();
      asm volatile("s_waitcnt lgkmcnt(0)" ::: "memory");
      __builtin_amdgcn_s_setprio(1);
#pragma unroll
      for (int i = 0; i < 4; ++i)
#pragma unroll
        for (int j = 0; j < 4; ++j)
          acc[i][j] = __builtin_amdgcn_mfma_f32_16x16x32_f16(af[i], bf[j], acc[i][j], 0, 0, 0);
      __builtin_amdgcn_s_setprio(0);
      __builtin_amdgcn_s_barrier();
    }
  }
#undef STAGE_A1
#undef STAGE_B1

  float bv[4];
#pragma unroll
  for (int nf = 0; nf < 4; ++nf) bv[nf] = bias[n0 + wc * 64 + nf * 16 + fr];
#pragma unroll
  for (int mf = 0; mf < 4; ++mf) {
#pragma unroll
    for (int r = 0; r < 4; ++r) {
      const int row = m0 + wr * 64 + mf * 16 + ((lane >> 4) << 2) + r;
      const size_t ro = (size_t)row * Nn;
#pragma unroll
      for (int nf = 0; nf < 4; ++nf) {
        const int col = n0 + wc * 64 + nf * 16 + fr;
        float u = acc[mf][nf][r] + bv[nf];
        if (GELU_EP) u = fast_gelu(u);
        if (RES) u += res[ro + col];
        if (OUT_HALF) ((_Float16*)Cout)[ro + col] = (_Float16)u;
        else          ((float*)Cout)[ro + col] = u;
      }
    }
  }
}

// ---------------- MFMA flash attention (fp16 in/out, fp32 softmax/acc) ----------------
__global__ __launch_bounds__(256) void mattn_kernel(const _Float16* __restrict__ qkv,
                                                    _Float16* __restrict__ ctx) {
  __shared__ __align__(16) _Float16 Ks[64][72];
  __shared__ __align__(16) _Float16 Vt[64][72];
  __shared__ __align__(16) _Float16 Ps[4][16][72];
  const int qt = blockIdx.x, h = blockIdx.y, b = blockIdx.z;
  const int tid = threadIdx.x;
  const int lane = tid & 63;
  const int w = tid >> 6;
  const int l15 = lane & 15;
  const int koff = (lane >> 4) * 8;

  const size_t qrow = (size_t)b * N_ + qt * 64 + w * 16 + l15;
  half8 qf0 = *reinterpret_cast<const half8*>(qkv + qrow * 3072 + h * 64 + koff);
  half8 qf1 = *reinterpret_cast<const half8*>(qkv + qrow * 3072 + h * 64 + 32 + koff);
  qf0 *= (_Float16)0.125f;
  qf1 *= (_Float16)0.125f;

  const int skey = tid >> 2;
  const int sch = (tid & 3) * 16;

  float m_i[4], l_i[4];
  f32x4 oacc[4];
#pragma unroll
  for (int r = 0; r < 4; ++r) { m_i[r] = -3.0e38f; l_i[r] = 0.0f; }
#pragma unroll
  for (int jb = 0; jb < 4; ++jb) oacc[jb] = (f32x4)0.0f;

  for (int kt = 0; kt < 16; ++kt) {
    __syncthreads();
    const _Float16* krow = qkv + ((size_t)b * N_ + kt * 64 + skey) * 3072 + 1024 + h * 64 + sch;
    half8 k0 = *reinterpret_cast<const half8*>(krow);
    half8 k1 = *reinterpret_cast<const half8*>(krow + 8);
    half8 v0 = *reinterpret_cast<const half8*>(krow + 1024);
    half8 v1 = *reinterpret_cast<const half8*>(krow + 1032);
    *reinterpret_cast<half8*>(&Ks[skey][sch]) = k0;
    *reinterpret_cast<half8*>(&Ks[skey][sch + 8]) = k1;
#pragma unroll
    for (int j = 0; j < 8; ++j) {
      Vt[sch + j][skey] = v0[j];
      Vt[sch + 8 + j][skey] = v1[j];
    }
    __syncthreads();

    f32x4 sacc[4];
#pragma unroll
    for (int jb = 0; jb < 4; ++jb) sacc[jb] = (f32x4)0.0f;
#pragma unroll
    for (int jb = 0; jb < 4; ++jb) {
      half8 kfa = *reinterpret_cast<const half8*>(&Ks[jb * 16 + l15][koff]);
      half8 kfb = *reinterpret_cast<const half8*>(&Ks[jb * 16 + l15][32 + koff]);
      sacc[jb] = __builtin_amdgcn_mfma_f32_16x16x32_f16(qf0, kfa, sacc[jb], 0, 0, 0);
      sacc[jb] = __builtin_amdgcn_mfma_f32_16x16x32_f16(qf1, kfb, sacc[jb], 0, 0, 0);
    }

    float p[4][4];
#pragma unroll
    for (int r = 0; r < 4; ++r) {
      float mx = fmaxf(fmaxf(sacc[0][r], sacc[1][r]), fmaxf(sacc[2][r], sacc[3][r]));
#pragma unroll
      for (int mk = 1; mk < 16; mk <<= 1) mx = fmaxf(mx, __shfl_xor(mx, mk, 64));
      const float nm = fmaxf(m_i[r], mx);
      const float scale = __expf(m_i[r] - nm);
      float rs = 0.0f;
#pragma unroll
      for (int jb = 0; jb < 4; ++jb) { p[jb][r] = __expf(sacc[jb][r] - nm); rs += p[jb][r]; }
#pragma unroll
      for (int mk = 1; mk < 16; mk <<= 1) rs += __shfl_xor(rs, mk, 64);
      l_i[r] = l_i[r] * scale + rs;
      m_i[r] = nm;
#pragma unroll
      for (int jb = 0; jb < 4; ++jb) oacc[jb][r] *= scale;
    }

#pragma unroll
    for (int jb = 0; jb < 4; ++jb)
#pragma unroll
      for (int r = 0; r < 4; ++r)
        Ps[w][(lane >> 4) * 4 + r][jb * 16 + l15] = (_Float16)p[jb][r];

    half8 pf0 = *reinterpret_cast<const half8*>(&Ps[w][l15][koff]);
    half8 pf1 = *reinterpret_cast<const half8*>(&Ps[w][l15][32 + koff]);
#pragma unroll
    for (int jb = 0; jb < 4; ++jb) {
      half8 vf0 = *reinterpret_cast<const half8*>(&Vt[jb * 16 + l15][koff]);
      half8 vf1 = *reinterpret_cast<const half8*>(&Vt[jb * 16 + l15][32 + koff]);
      oacc[jb] = __builtin_amdgcn_mfma_f32_16x16x32_f16(pf0, vf0, oacc[jb], 0, 0, 0);
      oacc[jb] = __builtin_amdgcn_mfma_f32_16x16x32_f16(pf1, vf1, oacc[jb], 0, 0, 0);
    }
  }

#pragma unroll
  for (int jb = 0; jb < 4; ++jb)
#pragma unroll
    for (int r = 0; r < 4; ++r) {
      const size_t orow = (size_t)b * N_ + qt * 64 + w * 16 + (lane >> 4) * 4 + r;
      ctx[orow * 1024 + h * 64 + jb * 16 + l15] = (_Float16)(oacc[jb][r] / l_i[r]);
    }
}

// ---------------- score ----------------
__global__ __launch_bounds__(256) void score_kernel(const float* __restrict__ hbuf,
                                                    const float* __restrict__ lw,
                                                    float* __restrict__ mp) {
  __shared__ float sh[4];
  const int row = blockIdx.x, tid = threadIdx.x;
  const float4 v = reinterpret_cast<const float4*>(hbuf + (size_t)row * D_)[tid];
  const float4 w = reinterpret_cast<const float4*>(lw)[tid];
  float s = v.x * w.x + v.y * w.y + v.z * w.z + v.w * w.w;
  s = waveSum(s);
  if ((tid & 63) == 0) sh[tid >> 6] = s;
  __syncthreads();
  if (tid == 0) mp[row] = sh[0] + sh[1] + sh[2] + sh[3];
}

// ---------------- lse over n of 2*(mp+g) ----------------
__global__ __launch_bounds__(256) void lse_kernel(const float* __restrict__ g,
                                                  const float* __restrict__ mp,
                                                  float* __restrict__ lse) {
  __shared__ float sh[4];
  const int row = blockIdx.x;          // k*8+b
  const int b = row & 7;
  const int tid = threadIdx.x;
  const float4 gv = reinterpret_cast<const float4*>(g + (size_t)row * 1024)[tid];
  const float4 mv = reinterpret_cast<const float4*>(mp + b * 1024)[tid];
  const float l0 = 2.0f * (gv.x + mv.x), l1 = 2.0f * (gv.y + mv.y);
  const float l2 = 2.0f * (gv.z + mv.z), l3 = 2.0f * (gv.w + mv.w);
  float mx = fmaxf(fmaxf(l0, l1), fmaxf(l2, l3));
  mx = waveMax(mx);
  if ((tid & 63) == 0) sh[tid >> 6] = mx;
  __syncthreads();
  mx = fmaxf(fmaxf(sh[0], sh[1]), fmaxf(sh[2], sh[3]));
  __syncthreads();
  float se = expf(l0 - mx) + expf(l1 - mx) + expf(l2 - mx) + expf(l3 - mx);
  se = waveSum(se);
  if ((tid & 63) == 0) sh[tid >> 6] = se;
  __syncthreads();
  if (tid == 0) lse[row] = mx + logf(sh[0] + sh[1] + sh[2] + sh[3]);
}

// ---------------- z two-stage ----------------
__global__ __launch_bounds__(256) void zpart_kernel(const float* __restrict__ g,
                                                    const float* __restrict__ lse,
                                                    float* __restrict__ pb) {
  const int idx = blockIdx.x * 256 + threadIdx.x;   // b*1024+n
  const int kc = blockIdx.y;                        // 0..15
  const int b = idx >> 10;
  float best = -3.0e38f;
#pragma unroll 8
  for (int k = kc * 32; k < kc * 32 + 32; ++k) {
    const float gv = g[(size_t)k * ROWS_ + idx];
    best = fmaxf(best, 2.0f * gv - lse[k * 8 + b]);
  }
  pb[(size_t)kc * ROWS_ + idx] = best;
}

__global__ __launch_bounds__(256) void zfin_kernel(const float* __restrict__ pb,
                                                   const float* __restrict__ mp,
                                                   float* __restrict__ z) {
  const int idx = blockIdx.x * 256 + threadIdx.x;
  float best = -3.0e38f;
#pragma unroll
  for (int kc = 0; kc < 16; ++kc) best = fmaxf(best, pb[(size_t)kc * ROWS_ + idx]);
  z[idx] = expf(2.0f * mp[idx] + best);
}

extern "C" void kernel_launch(void* const* d_in, const int* in_sizes, int n_in,
                              void* d_out, int out_size, void* d_ws, size_t ws_size,
                              hipStream_t stream) {
  (void)in_sizes; (void)n_in; (void)out_size; (void)ws_size;
  const float* f      = (const float*)d_in[0];
  const float* qkv_w  = (const float*)d_in[2];
  const float* qkv_b  = (const float*)d_in[3];
  const float* proj_w = (const float*)d_in[4];
  const float* proj_b = (const float*)d_in[5];
  const float* ln1_w  = (const float*)d_in[6];
  const float* ln1_b  = (const float*)d_in[7];
  const float* ln2_w  = (const float*)d_in[8];
  const float* ln2_b  = (const float*)d_in[9];
  const float* fc1_w  = (const float*)d_in[10];
  const float* fc1_b  = (const float*)d_in[11];
  const float* fc2_w  = (const float*)d_in[12];
  const float* fc2_b  = (const float*)d_in[13];
  const float* lin_w  = (const float*)d_in[14];
  float* out = (float*)d_out;

  // -------- workspace (f32 offsets; peak ~44.2M f32 = 177 MB) --------
  float* ws = (float*)d_ws;
  _Float16* wh = (_Float16*)d_ws;
  _Float16* QKVWH  = wh;                        // 3,145,728 h
  _Float16* PROJWH = wh + 3145728;              // 1,048,576 h
  _Float16* FC1WH  = wh + 4194304;              // 4,194,304 h
  _Float16* FC2WH  = wh + 8388608;              // 4,194,304 h -> ends f32 6,291,456
  float* MP  = ws + 6291456;                    // 8192
  float* LSE = ws + 6299648;                    // 4096
  _Float16* XH   = (_Float16*)(ws + 6303744);   // 8,388,608 h
  _Float16* QKVH = (_Float16*)(ws + 10498048);  // 25,165,824 h (dead after attn)
  _Float16* CTXH = (_Float16*)(ws + 23080960);  // 8,388,608 h
  _Float16* YH   = (_Float16*)(ws + 10498048);  // 16,777,216 h (reuses QKVH)
  float* F1   = ws + 27275264;                  // 8,388,608 f32
  float* Hbuf = ws + 35663872;                  // 8,388,608 f32 -> end 44,052,480
  float* PB   = ws + 44052480;                  // 131,072 f32 -> end 44,183,552
  float* G    = ws;                             // 4,194,304 f32 (weights dead by then)

  f2h_kernel<<<3072, 256, 0, stream>>>(qkv_w, QKVWH, 786432);
  f2h_kernel<<<1024, 256, 0, stream>>>(proj_w, PROJWH, 262144);
  f2h_kernel<<<4096, 256, 0, stream>>>(fc1_w, FC1WH, 1048576);
  f2h_kernel<<<4096, 256, 0, stream>>>(fc2_w, FC2WH, 1048576);

  ln_kernel<<<ROWS_, 256, 0, stream>>>(f, ln1_w, ln1_b, XH);
  // qkv: M=8192 N=3072 K=1024 -> 256x256, 384 blocks (4-phase control)
  hgemm8_kernel<false, false, true><<<384, 512, 0, stream>>>(XH, QKVWH, qkv_b, nullptr, QKVH, 3072, 1024, 12);
  mattn_kernel<<<dim3(16, 16, 8), 256, 0, stream>>>(QKVH, CTXH);
  // proj: M=8192 N=1024 K=1024 -> 128x256, 256 blocks (full machine)
  hgemm128_kernel<false, true, false><<<256, 512, 0, stream>>>(CTXH, PROJWH, proj_b, f, F1, 1024, 1024, 4);
  ln_kernel<<<ROWS_, 256, 0, stream>>>(F1, ln2_w, ln2_b, XH);
  // fc1: M=8192 N=4096 K=1024 -> 256x256, 512 blocks (2-phase-wide experiment)
  hgemm8w_kernel<true, false, true><<<512, 512, 0, stream>>>(XH, FC1WH, fc1_b, nullptr, YH, 4096, 1024, 16);
  // fc2: M=8192 N=1024 K=4096 -> 128x256, 256 blocks (full machine)
  hgemm128_kernel<false, true, false><<<256, 512, 0, stream>>>(YH, FC2WH, fc2_b, F1, Hbuf, 1024, 4096, 4);
  score_kernel<<<ROWS_, 256, 0, stream>>>(Hbuf, lin_w, MP);
  gumbel_kernel<<<GTOT / 256, 256, 0, stream>>>(G);
  lse_kernel<<<KD_ * B_, 256, 0, stream>>>(G, MP, LSE);
  zpart_kernel<<<dim3(ROWS_ / 256, 16), 256, 0, stream>>>(G, LSE, PB);
  zfin_kernel<<<ROWS_ / 256, 256, 0, stream>>>(PB, MP, out);
}